// Round 7
// baseline (402.578 us; speedup 1.0000x reference)
//
#include <hip/hip_runtime.h>
#include <math.h>

#define N_NODES 20
#define IN_DIM  9
#define HID     128
#define K_NBR   5
#define EPS     1e-5f
#define IPB     4          // items (waves) per 256-thread block

// ---- per-item LDS slice (bytes), regions with disjoint lifetimes alias at 0 ----
// phase A: xs (180 f32 = 720B @0) + adjx (20x16 bf16 = 640B @736)
// phase B: hrm  (20 rows x 136 bf16 = 5440B @0)   h row-major, A-operand for t=h@W2
// phase C: tT   (128 cols x 24 bf16 = 6144B @0)   t transposed, B-operand for adj@t
// guard   : 16B zeros @6144 (col127/q3 B-frag overread target; never clobbered)
#define ADJX_OFF  736
#define SLICE     6160
#define HTSTR     24       // tT row-slots per col (multiple of 8 -> b128-aligned reads)
#define HRSTR     136      // hrm row stride (272B: 16B-mult, 4 mod 32 banks -> 2-way free)

typedef __attribute__((ext_vector_type(8))) short short8;   // 8 bf16 (4 VGPRs)
typedef __attribute__((ext_vector_type(4))) float f32x4;    // MFMA C/D frag
typedef __attribute__((ext_vector_type(2))) unsigned int u32x2;
typedef __attribute__((ext_vector_type(4))) unsigned int u32x4;

#define WB() __builtin_amdgcn_wave_barrier()

__device__ __forceinline__ unsigned short f2bf(float f) {
    unsigned u = __builtin_bit_cast(unsigned, f);
    u += 0x7fffu + ((u >> 16) & 1u);          // RNE
    return (unsigned short)(u >> 16);
}
#if __has_builtin(__builtin_amdgcn_cvt_pk_bf16_f32)
typedef __attribute__((ext_vector_type(2))) __bf16 bf16x2;
__device__ __forceinline__ unsigned cvtpk(float a, float b) {   // low=bf16(a), hi=bf16(b)
    bf16x2 r = __builtin_amdgcn_cvt_pk_bf16_f32(a, b);
    return __builtin_bit_cast(unsigned, r);
}
#else
__device__ __forceinline__ unsigned cvtpk(float a, float b) {
    return (unsigned)f2bf(a) | ((unsigned)f2bf(b) << 16);
}
#endif
__device__ __forceinline__ float bf2f(unsigned short h) {
    return __builtin_bit_cast(float, (unsigned)h << 16);
}
// tanh-form GELU (|err| <~1e-3): x*u/(u+1), u=e^{2*0.79788456*(x+0.044715x^3)}
__device__ __forceinline__ float gelu_fast(float x) {
    float x2 = x * x;
    float y  = x * fmaf(x2, 0.07135806592f, 1.5957691216f);
    float u  = __expf(fminf(y, 60.0f));
    return x * u * __builtin_amdgcn_rcpf(u + 1.0f);
}

__device__ __forceinline__ f32x4 mfma16(short8 a, short8 b, f32x4 c) {
    return __builtin_amdgcn_mfma_f32_16x16x32_bf16(a, b, c, 0, 0, 0);
}

// ===== single prep kernel (no inter-kernel deps, fully parallel) =====
// wswM1[nt*512 + lane*8 + j] = bf16(M1[k][n]), M1 = We@W1 (9x128), k=(lane>>4)*8+j (0 if k>=9),
//                              n = nt*16 + (lane&15)
// wsw2 [(ks*8+nt)*512 + lane*8 + j] = bf16(w2[k][n]), k=ks*32+(lane>>4)*8+j
// c1f[n] = 5*(be@W1)[n] + b1[n]
__global__ void prep_all(const float* __restrict__ w_embed, const float* __restrict__ b_embed,
                         const float* __restrict__ w1, const float* __restrict__ b1,
                         const float* __restrict__ w2,
                         unsigned short* __restrict__ wswM1, unsigned short* __restrict__ wsw2,
                         float* __restrict__ c1f) {
    int idx = blockIdx.x * 256 + threadIdx.x;          // 20608 total
    if (idx < 4096) {
        int j = idx & 7, lane = (idx >> 3) & 63, nt = (idx >> 9) & 7;
        int k = (lane >> 4) * 8 + j;
        int n = nt * 16 + (lane & 15);
        unsigned short r = 0;
        if (k < IN_DIM) {
            float acc = 0.f;
            for (int c = 0; c < HID; ++c)
                acc = fmaf(w_embed[k*HID + c], w1[c*HID + n], acc);
            r = f2bf(acc);
        }
        wswM1[idx] = r;
    } else if (idx < 4096 + 16384) {
        int i2 = idx - 4096;
        int j = i2 & 7, lane = (i2 >> 3) & 63, nt = (i2 >> 9) & 7, ks = (i2 >> 12) & 3;
        int k = ks * 32 + (lane >> 4) * 8 + j;
        int n = nt * 16 + (lane & 15);
        wsw2[i2] = f2bf(w2[k*HID + n]);
    } else if (idx < 4096 + 16384 + 128) {
        int n = idx - (4096 + 16384);
        float cb = 0.f;
        for (int c = 0; c < HID; ++c)
            cb = fmaf(b_embed[c], w1[c*HID + n], cb);
        c1f[n] = 5.0f * cb + b1[n];
    }
}

// ===== main =====
__global__ __launch_bounds__(256, 4) void hbond_main(
    const float* __restrict__ x_in,
    const float* __restrict__ c1f, const float* __restrict__ b2,
    const float* __restrict__ g1, const float* __restrict__ be1,
    const float* __restrict__ g2, const float* __restrict__ be2,
    const unsigned short* __restrict__ wswM1, const unsigned short* __restrict__ wsw2,
    float* __restrict__ out, int nItems)
{
    __shared__ __align__(16) unsigned char smem[IPB * SLICE];

    const int l  = threadIdx.x & 63;
    const int wv = threadIdx.x >> 6;
    const int item = blockIdx.x * IPB + wv;
    if (item >= nItems) return;               // wave-uniform; no cross-wave barriers

    unsigned char* slice = smem + wv * SLICE;
    float*          xs   = (float*)(slice);                    // phase A
    unsigned short* adjx = (unsigned short*)(slice + ADJX_OFF);// phase A
    unsigned short* hrm  = (unsigned short*)(slice);           // phase B (aliases A)
    unsigned short* tT   = (unsigned short*)(slice);           // phase C (aliases B)

    const int ln15 = l & 15, q = l >> 4;
    const float* xb = x_in + (size_t)item * (N_NODES * IN_DIM);

    // guard for tT col127/q3 overread (bytes 6144..6160); hrm/tT stay below it
    if (l == 0) *(u32x4*)(slice + HTSTR * HID * 2) = (u32x4){0,0,0,0};

    // ---- stage x: 180 floats ----
    if (l < 45) ((float4*)xs)[l] = ((const float4*)xb)[l];
    WB();

    // ---- KNN: lane r = row r (r<20); bit-safe d2; tie -> lower index ----
    unsigned nbrp = 0;                        // 5 x 5-bit neighbor indices
    {
        const int rsel = (l < N_NODES) ? l : 0;
        const float px = xs[rsel*IN_DIM+6], py = xs[rsel*IN_DIM+7], pz = xs[rsel*IN_DIM+8];
        float d2[N_NODES];
        #pragma unroll
        for (int j = 0; j < N_NODES; ++j) {
            float dx = __fsub_rn(px, __shfl(px, j));
            float dy = __fsub_rn(py, __shfl(py, j));
            float dz = __fsub_rn(pz, __shfl(pz, j));
            d2[j] = __fadd_rn(__fadd_rn(__fmul_rn(dx,dx), __fmul_rn(dy,dy)), __fmul_rn(dz,dz));
        }
        unsigned used = 0u;
        #pragma unroll
        for (int k = 0; k < K_NBR; ++k) {
            float best = INFINITY; int bi = 0;
            #pragma unroll
            for (int j = 0; j < N_NODES; ++j) {
                bool take = (!((used >> j) & 1u)) && (d2[j] < best);
                best = take ? d2[j] : best;
                bi   = take ? j     : bi;
            }
            used |= (1u << bi);
            nbrp |= (unsigned)bi << (5*k);
        }
    }

    // ---- adjacency bitmask + bf16 A-fragments (k=q*8+j; bits >=20 always 0) ----
    unsigned amask = 0;
    #pragma unroll
    for (int j = 0; j < K_NBR; ++j) amask |= 1u << ((nbrp >> (5*j)) & 31);
    const unsigned am0 = (unsigned)__shfl((int)amask, ln15);
    const unsigned am1 = (unsigned)__shfl((int)amask, ln15 + 16); // rows>=20: finite garbage, discarded
    short8 adjf0, adjf1;
    #pragma unroll
    for (int j = 0; j < 8; ++j) {
        adjf0[j] = (short)(((am0 >> (q*8 + j)) & 1u) ? 0x3F80 : 0);
        adjf1[j] = (short)(((am1 >> (q*8 + j)) & 1u) ? 0x3F80 : 0);
    }

    // ---- agg1 on raw x (fp32 exact): adjx[r][c] = sum_{5 nbrs} x[nj][c] ----
    if (l < N_NODES) {
        float s[IN_DIM];
        #pragma unroll
        for (int c = 0; c < IN_DIM; ++c) s[c] = 0.f;
        #pragma unroll
        for (int j = 0; j < K_NBR; ++j) {
            const int nj = (nbrp >> (5*j)) & 31;
            #pragma unroll
            for (int c = 0; c < IN_DIM; ++c) s[c] += xs[nj*IN_DIM + c];
        }
        u32x4 p0 = { cvtpk(s[0],s[1]), cvtpk(s[2],s[3]), cvtpk(s[4],s[5]), cvtpk(s[6],s[7]) };
        u32x4 p1 = { cvtpk(s[8],0.f), 0, 0, 0 };
        *(u32x4*)&adjx[l*16 + 0] = p0;
        *(u32x4*)&adjx[l*16 + 8] = p1;
    }
    WB();

    f32x4 acc[2][8];
    const int rlo = ln15, rhi = (ln15 + 16 > 19) ? 19 : ln15 + 16;  // clamp garbage rows

    // ---- GEMM1: y1 = adjx @ M1 + c1  (K=32, 16 MFMA; B zero for k>=9) ----
    {
        const short8 a0 = *(const short8*)&adjx[rlo*16 + (q & 1)*8];
        const short8 a1 = *(const short8*)&adjx[rhi*16 + (q & 1)*8];
        #pragma unroll
        for (int nt = 0; nt < 8; ++nt) {
            const float bv = c1f[ln15 + 16*nt];
            f32x4 c0 = (f32x4){bv, bv, bv, bv};
            const short8 bfr = *(const short8*)&wswM1[nt*512 + l*8];
            acc[0][nt] = mfma16(a0, bfr, c0);
            acc[1][nt] = mfma16(a1, bfr, c0);
        }
    }

    // ---- LN1 + GELU (C-layout regs) -> h ----
    {
        float gv[8], bv[8];
        #pragma unroll
        for (int nt = 0; nt < 8; ++nt) { gv[nt] = g1[ln15+16*nt]; bv[nt] = be1[ln15+16*nt]; }
        #pragma unroll
        for (int mt = 0; mt < 2; ++mt) {
            #pragma unroll
            for (int reg = 0; reg < 4; ++reg) {
                float s = 0.f, sq = 0.f;
                #pragma unroll
                for (int nt = 0; nt < 8; ++nt) { float v = acc[mt][nt][reg]; s += v; sq += v*v; }
                #pragma unroll
                for (int m = 1; m < 16; m <<= 1) { s += __shfl_xor(s, m); sq += __shfl_xor(sq, m); }
                const float mean = s * (1.f/HID);
                const float var  = sq * (1.f/HID) - mean*mean;
                const float rstd = rsqrtf(fmaxf(var, 0.f) + EPS);
                #pragma unroll
                for (int nt = 0; nt < 8; ++nt)
                    acc[mt][nt][reg] = gelu_fast((acc[mt][nt][reg] - mean)*rstd*gv[nt] + bv[nt]);
            }
        }
    }

    // ---- keep h packed in regs (bf16 pairs) for the final residual ----
    unsigned hp0[8][2], hp1[8][2];
    #pragma unroll
    for (int nt = 0; nt < 8; ++nt) {
        hp0[nt][0] = cvtpk(acc[0][nt][0], acc[0][nt][1]);
        hp0[nt][1] = cvtpk(acc[0][nt][2], acc[0][nt][3]);
        hp1[nt][0] = cvtpk(acc[1][nt][0], acc[1][nt][1]);
        hp1[nt][1] = cvtpk(acc[1][nt][2], acc[1][nt][3]);
    }
    WB();   // adjx/xs dead; GEMM1 A-reads complete

    // ---- scatter h (C-layout) -> hrm row-major (rows 0..19 only) ----
    #pragma unroll
    for (int nt = 0; nt < 8; ++nt) {
        const int col = ln15 + 16*nt;
        hrm[(q*4+0)*HRSTR + col] = (unsigned short)hp0[nt][0];
        hrm[(q*4+1)*HRSTR + col] = (unsigned short)(hp0[nt][0] >> 16);
        hrm[(q*4+2)*HRSTR + col] = (unsigned short)hp0[nt][1];
        hrm[(q*4+3)*HRSTR + col] = (unsigned short)(hp0[nt][1] >> 16);
        if (q == 0) {
            hrm[16*HRSTR + col] = (unsigned short)hp1[nt][0];
            hrm[17*HRSTR + col] = (unsigned short)(hp1[nt][0] >> 16);
            hrm[18*HRSTR + col] = (unsigned short)hp1[nt][1];
            hrm[19*HRSTR + col] = (unsigned short)(hp1[nt][1] >> 16);
        }
    }
    WB();

    // ---- GEMM2': t = h @ W2  (K=128, 64 MFMA; garbage rows clamped) ----
    #pragma unroll
    for (int nt = 0; nt < 8; ++nt) { acc[0][nt] = (f32x4){0,0,0,0}; acc[1][nt] = acc[0][nt]; }
    #pragma unroll
    for (int ks = 0; ks < 4; ++ks) {
        const short8 a0 = *(const short8*)&hrm[rlo*HRSTR + ks*32 + q*8];
        const short8 a1 = *(const short8*)&hrm[rhi*HRSTR + ks*32 + q*8];
        #pragma unroll
        for (int nt = 0; nt < 8; ++nt) {
            const short8 bfr = *(const short8*)&wsw2[(ks*8 + nt)*512 + l*8];
            acc[0][nt] = mfma16(a0, bfr, acc[0][nt]);
            acc[1][nt] = mfma16(a1, bfr, acc[1][nt]);
        }
    }
    WB();   // all hrm reads complete; tT may overwrite

    // ---- store t transposed: tT[col][row] (cheap u32x2 stores) ----
    #pragma unroll
    for (int nt = 0; nt < 8; ++nt) {
        const int col = ln15 + 16*nt;
        u32x2 w0 = { cvtpk(acc[0][nt][0], acc[0][nt][1]), cvtpk(acc[0][nt][2], acc[0][nt][3]) };
        *(u32x2*)&tT[col*HTSTR + q*4] = w0;                        // rows q*4..q*4+3
        if (q == 0) {
            u32x2 w1v = { cvtpk(acc[1][nt][0], acc[1][nt][1]), cvtpk(acc[1][nt][2], acc[1][nt][3]) };
            *(u32x2*)&tT[col*HTSTR + 16] = w1v;                    // rows 16..19
        }
    }
    // zero row-slots 20..23 for every col (lane covers col l and col l+64).
    // REQUIRED even though adjacency A-bits >=20 are zero: stale bytes can
    // encode bf16 Inf/NaN and IEEE 0*Inf = NaN would poison the MFMA dot.
    *(u32x2*)&tT[l*HTSTR + 20]        = (u32x2){0,0};
    *(u32x2*)&tT[(l + 64)*HTSTR + 20] = (u32x2){0,0};
    WB();

    // ---- y2 = adj @ t + b2  (16 MFMA) ----
    f32x4 acc2[2][8];
    #pragma unroll
    for (int nt = 0; nt < 8; ++nt) {
        const float bv = b2[ln15 + 16*nt];
        f32x4 c0 = (f32x4){bv, bv, bv, bv};
        const short8 bfr = *(const short8*)&tT[(ln15 + 16*nt)*HTSTR + q*8];  // k=q*8+j
        acc2[0][nt] = mfma16(adjf0, bfr, c0);
        acc2[1][nt] = mfma16(adjf1, bfr, c0);
    }

    // ---- LN2 ----
    {
        float gv[8], bv[8];
        #pragma unroll
        for (int nt = 0; nt < 8; ++nt) { gv[nt] = g2[ln15+16*nt]; bv[nt] = be2[ln15+16*nt]; }
        #pragma unroll
        for (int mt = 0; mt < 2; ++mt) {
            #pragma unroll
            for (int reg = 0; reg < 4; ++reg) {
                float s = 0.f, sq = 0.f;
                #pragma unroll
                for (int nt = 0; nt < 8; ++nt) { float v = acc2[mt][nt][reg]; s += v; sq += v*v; }
                #pragma unroll
                for (int m = 1; m < 16; m <<= 1) { s += __shfl_xor(s, m); sq += __shfl_xor(sq, m); }
                const float mean = s * (1.f/HID);
                const float var  = sq * (1.f/HID) - mean*mean;
                const float rstd = rsqrtf(fmaxf(var, 0.f) + EPS);
                #pragma unroll
                for (int nt = 0; nt < 8; ++nt)
                    acc2[mt][nt][reg] = (acc2[mt][nt][reg] - mean)*rstd*gv[nt] + bv[nt];
            }
        }
    }

    // ---- final: gelu(h + LN2), max over rows, store ----
    #pragma unroll
    for (int nt = 0; nt < 8; ++nt) {
        float m0 = -INFINITY;
        m0 = fmaxf(m0, gelu_fast(bf2f((unsigned short)hp0[nt][0])         + acc2[0][nt][0]));
        m0 = fmaxf(m0, gelu_fast(bf2f((unsigned short)(hp0[nt][0] >> 16)) + acc2[0][nt][1]));
        m0 = fmaxf(m0, gelu_fast(bf2f((unsigned short)hp0[nt][1])         + acc2[0][nt][2]));
        m0 = fmaxf(m0, gelu_fast(bf2f((unsigned short)(hp0[nt][1] >> 16)) + acc2[0][nt][3]));
        if (q == 0) {
            m0 = fmaxf(m0, gelu_fast(bf2f((unsigned short)hp1[nt][0])         + acc2[1][nt][0]));
            m0 = fmaxf(m0, gelu_fast(bf2f((unsigned short)(hp1[nt][0] >> 16)) + acc2[1][nt][1]));
            m0 = fmaxf(m0, gelu_fast(bf2f((unsigned short)hp1[nt][1])         + acc2[1][nt][2]));
            m0 = fmaxf(m0, gelu_fast(bf2f((unsigned short)(hp1[nt][1] >> 16)) + acc2[1][nt][3]));
        }
        m0 = fmaxf(m0, __shfl_xor(m0, 16));
        m0 = fmaxf(m0, __shfl_xor(m0, 32));
        if (l < 16) out[(size_t)item*HID + 16*nt + l] = m0;
    }
}

extern "C" void kernel_launch(void* const* d_in, const int* in_sizes, int n_in,
                              void* d_out, int out_size, void* d_ws, size_t ws_size,
                              hipStream_t stream) {
    (void)n_in; (void)out_size; (void)ws_size;
    const float* x       = (const float*)d_in[0];
    const float* w_embed = (const float*)d_in[1];
    const float* b_embed = (const float*)d_in[2];
    const float* w1      = (const float*)d_in[3];
    const float* b1      = (const float*)d_in[4];
    const float* w2      = (const float*)d_in[5];
    const float* b2      = (const float*)d_in[6];
    const float* g1      = (const float*)d_in[7];
    const float* be1     = (const float*)d_in[8];
    const float* g2      = (const float*)d_in[9];
    const float* be2     = (const float*)d_in[10];
    float* out = (float*)d_out;

    // ws layout: [c1f 512B][wswM1 8192B][wsw2 32768B]
    unsigned char* ws = (unsigned char*)d_ws;
    float* c1f            = (float*)(ws + 0);
    unsigned short* wswM1 = (unsigned short*)(ws + 512);
    unsigned short* wsw2  = (unsigned short*)(ws + 512 + 8192);

    const int nItems  = in_sizes[0] / (N_NODES * IN_DIM);
    const int nBlocks = (nItems + IPB - 1) / IPB;

    prep_all<<<dim3(81), dim3(256), 0, stream>>>(w_embed, b_embed, w1, b1, w2,
                                                 wswM1, wsw2, c1f);
    hbond_main<<<dim3(nBlocks), dim3(256), 0, stream>>>(
        x, c1f, b2, g1, be1, g2, be2, wswM1, wsw2, out, nItems);
}

// Round 8
// 355.800 us; speedup vs baseline: 1.1315x; 1.1315x over previous
//
#include <hip/hip_runtime.h>
#include <math.h>

#define N_NODES 20
#define IN_DIM  9
#define HID     128
#define K_NBR   5
#define EPS     1e-5f
#define IPB     4          // items (waves) per 256-thread block

// ---- per-item LDS slice (bytes), regions with disjoint lifetimes alias at 0 ----
// phase A: xs (180 f32 = 720B @0) + adjx (20x16 bf16 = 640B @736)
// phase B: hrm  (20 rows x 136 bf16 = 5440B @0)   h row-major, A-operand for t=h@W2
// phase C: tT   (128 cols x 24 bf16 = 6144B @0)   t transposed, B-operand for adj@t
// guard   : 16B zeros @6144 (col127/q3 B-frag overread target; never clobbered)
#define ADJX_OFF  736
#define SLICE     6160
#define HTSTR     24       // tT row-slots per col (multiple of 8 -> b128-aligned reads)
#define HRSTR     136      // hrm row stride (272B: 16B-mult, 4 mod 32 banks -> 2-way free)

typedef __attribute__((ext_vector_type(8))) short short8;   // 8 bf16 (4 VGPRs)
typedef __attribute__((ext_vector_type(4))) float f32x4;    // MFMA C/D frag
typedef __attribute__((ext_vector_type(2))) unsigned int u32x2;
typedef __attribute__((ext_vector_type(4))) unsigned int u32x4;

#define WB() __builtin_amdgcn_wave_barrier()

__device__ __forceinline__ unsigned short f2bf(float f) {
    unsigned u = __builtin_bit_cast(unsigned, f);
    u += 0x7fffu + ((u >> 16) & 1u);          // RNE
    return (unsigned short)(u >> 16);
}
#if __has_builtin(__builtin_amdgcn_cvt_pk_bf16_f32)
typedef __attribute__((ext_vector_type(2))) __bf16 bf16x2;
__device__ __forceinline__ unsigned cvtpk(float a, float b) {   // low=bf16(a), hi=bf16(b)
    bf16x2 r = __builtin_amdgcn_cvt_pk_bf16_f32(a, b);
    return __builtin_bit_cast(unsigned, r);
}
#else
__device__ __forceinline__ unsigned cvtpk(float a, float b) {
    return (unsigned)f2bf(a) | ((unsigned)f2bf(b) << 16);
}
#endif
__device__ __forceinline__ float bf2f(unsigned short h) {
    return __builtin_bit_cast(float, (unsigned)h << 16);
}
// tanh-form GELU (|err| <~1e-3): x*u/(u+1), u=e^{2*0.79788456*(x+0.044715x^3)}
__device__ __forceinline__ float gelu_fast(float x) {
    float x2 = x * x;
    float y  = x * fmaf(x2, 0.07135806592f, 1.5957691216f);
    float u  = __expf(fminf(y, 60.0f));
    return x * u * __builtin_amdgcn_rcpf(u + 1.0f);
}

__device__ __forceinline__ f32x4 mfma16(short8 a, short8 b, f32x4 c) {
    return __builtin_amdgcn_mfma_f32_16x16x32_bf16(a, b, c, 0, 0, 0);
}

// ===== single prep kernel (no inter-kernel deps, fully parallel) =====
// wswM1[nt*512 + lane*8 + j] = bf16(M1[k][n]), M1 = We@W1 (9x128), k=(lane>>4)*8+j (0 if k>=9),
//                              n = nt*16 + (lane&15)
// wsw2 [(ks*8+nt)*512 + lane*8 + j] = bf16(w2[k][n]), k=ks*32+(lane>>4)*8+j
// c1f[n] = 5*(be@W1)[n] + b1[n]
__global__ void prep_all(const float* __restrict__ w_embed, const float* __restrict__ b_embed,
                         const float* __restrict__ w1, const float* __restrict__ b1,
                         const float* __restrict__ w2,
                         unsigned short* __restrict__ wswM1, unsigned short* __restrict__ wsw2,
                         float* __restrict__ c1f) {
    int idx = blockIdx.x * 256 + threadIdx.x;          // 20608 total
    if (idx < 4096) {
        int j = idx & 7, lane = (idx >> 3) & 63, nt = (idx >> 9) & 7;
        int k = (lane >> 4) * 8 + j;
        int n = nt * 16 + (lane & 15);
        unsigned short r = 0;
        if (k < IN_DIM) {
            float acc = 0.f;
            for (int c = 0; c < HID; ++c)
                acc = fmaf(w_embed[k*HID + c], w1[c*HID + n], acc);
            r = f2bf(acc);
        }
        wswM1[idx] = r;
    } else if (idx < 4096 + 16384) {
        int i2 = idx - 4096;
        int j = i2 & 7, lane = (i2 >> 3) & 63, nt = (i2 >> 9) & 7, ks = (i2 >> 12) & 3;
        int k = ks * 32 + (lane >> 4) * 8 + j;
        int n = nt * 16 + (lane & 15);
        wsw2[i2] = f2bf(w2[k*HID + n]);
    } else if (idx < 4096 + 16384 + 128) {
        int n = idx - (4096 + 16384);
        float cb = 0.f;
        for (int c = 0; c < HID; ++c)
            cb = fmaf(b_embed[c], w1[c*HID + n], cb);
        c1f[n] = 5.0f * cb + b1[n];
    }
}

// ===== main =====
// launch_bounds (256, 3): 3 waves/EU -> ~170 unified VGPR cap. (256,4) capped at 128
// and forced ~15.5 KB/item scratch spills (round 7: WRITE_SIZE 508 MB, HBM-bound).
__global__ __launch_bounds__(256, 3) void hbond_main(
    const float* __restrict__ x_in,
    const float* __restrict__ c1f, const float* __restrict__ b2,
    const float* __restrict__ g1, const float* __restrict__ be1,
    const float* __restrict__ g2, const float* __restrict__ be2,
    const unsigned short* __restrict__ wswM1, const unsigned short* __restrict__ wsw2,
    float* __restrict__ out, int nItems)
{
    __shared__ __align__(16) unsigned char smem[IPB * SLICE];

    const int l  = threadIdx.x & 63;
    const int wv = threadIdx.x >> 6;
    const int item = blockIdx.x * IPB + wv;
    if (item >= nItems) return;               // wave-uniform; no cross-wave barriers

    unsigned char* slice = smem + wv * SLICE;
    float*          xs   = (float*)(slice);                    // phase A
    unsigned short* adjx = (unsigned short*)(slice + ADJX_OFF);// phase A
    unsigned short* hrm  = (unsigned short*)(slice);           // phase B (aliases A)
    unsigned short* tT   = (unsigned short*)(slice);           // phase C (aliases B)

    const int ln15 = l & 15, q = l >> 4;
    const float* xb = x_in + (size_t)item * (N_NODES * IN_DIM);

    // guard for tT col127/q3 overread (bytes 6144..6160); hrm/tT stay below it
    if (l == 0) *(u32x4*)(slice + HTSTR * HID * 2) = (u32x4){0,0,0,0};

    // ---- stage x: 180 floats ----
    if (l < 45) ((float4*)xs)[l] = ((const float4*)xb)[l];
    WB();

    // ---- KNN: lane r = row r (r<20); bit-safe d2; tie -> lower index ----
    unsigned nbrp = 0;                        // 5 x 5-bit neighbor indices
    {
        const int rsel = (l < N_NODES) ? l : 0;
        const float px = xs[rsel*IN_DIM+6], py = xs[rsel*IN_DIM+7], pz = xs[rsel*IN_DIM+8];
        float d2[N_NODES];
        #pragma unroll
        for (int j = 0; j < N_NODES; ++j) {
            float dx = __fsub_rn(px, __shfl(px, j));
            float dy = __fsub_rn(py, __shfl(py, j));
            float dz = __fsub_rn(pz, __shfl(pz, j));
            d2[j] = __fadd_rn(__fadd_rn(__fmul_rn(dx,dx), __fmul_rn(dy,dy)), __fmul_rn(dz,dz));
        }
        unsigned used = 0u;
        #pragma unroll
        for (int k = 0; k < K_NBR; ++k) {
            float best = INFINITY; int bi = 0;
            #pragma unroll
            for (int j = 0; j < N_NODES; ++j) {
                bool take = (!((used >> j) & 1u)) && (d2[j] < best);
                best = take ? d2[j] : best;
                bi   = take ? j     : bi;
            }
            used |= (1u << bi);
            nbrp |= (unsigned)bi << (5*k);
        }
    }

    // ---- adjacency bitmask + bf16 A-fragments (k=q*8+j; bits >=20 always 0) ----
    unsigned amask = 0;
    #pragma unroll
    for (int j = 0; j < K_NBR; ++j) amask |= 1u << ((nbrp >> (5*j)) & 31);
    const unsigned am0 = (unsigned)__shfl((int)amask, ln15);
    const unsigned am1 = (unsigned)__shfl((int)amask, ln15 + 16); // rows>=20: garbage, discarded
    short8 adjf0, adjf1;
    #pragma unroll
    for (int j = 0; j < 8; ++j) {
        adjf0[j] = (short)(((am0 >> (q*8 + j)) & 1u) ? 0x3F80 : 0);
        adjf1[j] = (short)(((am1 >> (q*8 + j)) & 1u) ? 0x3F80 : 0);
    }

    // ---- agg1 on raw x (fp32 exact): adjx[r][c] = sum_{5 nbrs} x[nj][c] ----
    if (l < N_NODES) {
        float s[IN_DIM];
        #pragma unroll
        for (int c = 0; c < IN_DIM; ++c) s[c] = 0.f;
        #pragma unroll
        for (int j = 0; j < K_NBR; ++j) {
            const int nj = (nbrp >> (5*j)) & 31;
            #pragma unroll
            for (int c = 0; c < IN_DIM; ++c) s[c] += xs[nj*IN_DIM + c];
        }
        u32x4 p0 = { cvtpk(s[0],s[1]), cvtpk(s[2],s[3]), cvtpk(s[4],s[5]), cvtpk(s[6],s[7]) };
        u32x4 p1 = { cvtpk(s[8],0.f), 0, 0, 0 };
        *(u32x4*)&adjx[l*16 + 0] = p0;
        *(u32x4*)&adjx[l*16 + 8] = p1;
    }
    WB();

    f32x4 acc[2][8];
    const int rlo = ln15, rhi = (ln15 + 16 > 19) ? 19 : ln15 + 16;  // clamp garbage rows

    // ---- GEMM1: y1 = adjx @ M1 + c1  (K=32, 16 MFMA; B zero for k>=9) ----
    {
        const short8 a0 = *(const short8*)&adjx[rlo*16 + (q & 1)*8];
        const short8 a1 = *(const short8*)&adjx[rhi*16 + (q & 1)*8];
        #pragma unroll
        for (int nt = 0; nt < 8; ++nt) {
            const float bv = c1f[ln15 + 16*nt];
            f32x4 c0 = (f32x4){bv, bv, bv, bv};
            const short8 bfr = *(const short8*)&wswM1[nt*512 + l*8];
            acc[0][nt] = mfma16(a0, bfr, c0);
            acc[1][nt] = mfma16(a1, bfr, c0);
        }
    }

    // ---- LN1 + GELU (C-layout regs) -> h ----
    {
        float gv[8], bv[8];
        #pragma unroll
        for (int nt = 0; nt < 8; ++nt) { gv[nt] = g1[ln15+16*nt]; bv[nt] = be1[ln15+16*nt]; }
        #pragma unroll
        for (int mt = 0; mt < 2; ++mt) {
            #pragma unroll
            for (int reg = 0; reg < 4; ++reg) {
                float s = 0.f, sq = 0.f;
                #pragma unroll
                for (int nt = 0; nt < 8; ++nt) { float v = acc[mt][nt][reg]; s += v; sq += v*v; }
                #pragma unroll
                for (int m = 1; m < 16; m <<= 1) { s += __shfl_xor(s, m); sq += __shfl_xor(sq, m); }
                const float mean = s * (1.f/HID);
                const float var  = sq * (1.f/HID) - mean*mean;
                const float rstd = rsqrtf(fmaxf(var, 0.f) + EPS);
                #pragma unroll
                for (int nt = 0; nt < 8; ++nt)
                    acc[mt][nt][reg] = gelu_fast((acc[mt][nt][reg] - mean)*rstd*gv[nt] + bv[nt]);
            }
        }
    }

    // ---- keep h packed in regs (bf16 pairs) for the final residual ----
    unsigned hp0[8][2], hp1[8][2];
    #pragma unroll
    for (int nt = 0; nt < 8; ++nt) {
        hp0[nt][0] = cvtpk(acc[0][nt][0], acc[0][nt][1]);
        hp0[nt][1] = cvtpk(acc[0][nt][2], acc[0][nt][3]);
        hp1[nt][0] = cvtpk(acc[1][nt][0], acc[1][nt][1]);
        hp1[nt][1] = cvtpk(acc[1][nt][2], acc[1][nt][3]);
    }
    WB();   // adjx/xs dead; GEMM1 A-reads complete

    // ---- scatter h (C-layout) -> hrm row-major (rows 0..19 only) ----
    #pragma unroll
    for (int nt = 0; nt < 8; ++nt) {
        const int col = ln15 + 16*nt;
        hrm[(q*4+0)*HRSTR + col] = (unsigned short)hp0[nt][0];
        hrm[(q*4+1)*HRSTR + col] = (unsigned short)(hp0[nt][0] >> 16);
        hrm[(q*4+2)*HRSTR + col] = (unsigned short)hp0[nt][1];
        hrm[(q*4+3)*HRSTR + col] = (unsigned short)(hp0[nt][1] >> 16);
        if (q == 0) {
            hrm[16*HRSTR + col] = (unsigned short)hp1[nt][0];
            hrm[17*HRSTR + col] = (unsigned short)(hp1[nt][0] >> 16);
            hrm[18*HRSTR + col] = (unsigned short)hp1[nt][1];
            hrm[19*HRSTR + col] = (unsigned short)(hp1[nt][1] >> 16);
        }
    }
    WB();

    // ---- GEMM2': t = h @ W2  (K=128, 64 MFMA; garbage rows clamped) ----
    #pragma unroll
    for (int nt = 0; nt < 8; ++nt) { acc[0][nt] = (f32x4){0,0,0,0}; acc[1][nt] = acc[0][nt]; }
    #pragma unroll
    for (int ks = 0; ks < 4; ++ks) {
        const short8 a0 = *(const short8*)&hrm[rlo*HRSTR + ks*32 + q*8];
        const short8 a1 = *(const short8*)&hrm[rhi*HRSTR + ks*32 + q*8];
        #pragma unroll
        for (int nt = 0; nt < 8; ++nt) {
            const short8 bfr = *(const short8*)&wsw2[(ks*8 + nt)*512 + l*8];
            acc[0][nt] = mfma16(a0, bfr, acc[0][nt]);
            acc[1][nt] = mfma16(a1, bfr, acc[1][nt]);
        }
    }
    WB();   // all hrm reads complete; tT may overwrite

    // ---- store t transposed: tT[col][row] (cheap u32x2 stores) ----
    #pragma unroll
    for (int nt = 0; nt < 8; ++nt) {
        const int col = ln15 + 16*nt;
        u32x2 w0 = { cvtpk(acc[0][nt][0], acc[0][nt][1]), cvtpk(acc[0][nt][2], acc[0][nt][3]) };
        *(u32x2*)&tT[col*HTSTR + q*4] = w0;                        // rows q*4..q*4+3
        if (q == 0) {
            u32x2 w1v = { cvtpk(acc[1][nt][0], acc[1][nt][1]), cvtpk(acc[1][nt][2], acc[1][nt][3]) };
            *(u32x2*)&tT[col*HTSTR + 16] = w1v;                    // rows 16..19
        }
    }
    // zero row-slots 20..23 for every col (lane covers col l and col l+64).
    // REQUIRED even though adjacency A-bits >=20 are zero: stale bytes can
    // encode bf16 Inf/NaN and IEEE 0*Inf = NaN would poison the MFMA dot.
    *(u32x2*)&tT[l*HTSTR + 20]        = (u32x2){0,0};
    *(u32x2*)&tT[(l + 64)*HTSTR + 20] = (u32x2){0,0};
    WB();

    // ---- y2 = adj @ t + b2  (16 MFMA) ----
    f32x4 acc2[2][8];
    #pragma unroll
    for (int nt = 0; nt < 8; ++nt) {
        const float bv = b2[ln15 + 16*nt];
        f32x4 c0 = (f32x4){bv, bv, bv, bv};
        const short8 bfr = *(const short8*)&tT[(ln15 + 16*nt)*HTSTR + q*8];  // k=q*8+j
        acc2[0][nt] = mfma16(adjf0, bfr, c0);
        acc2[1][nt] = mfma16(adjf1, bfr, c0);
    }

    // ---- LN2 ----
    {
        float gv[8], bv[8];
        #pragma unroll
        for (int nt = 0; nt < 8; ++nt) { gv[nt] = g2[ln15+16*nt]; bv[nt] = be2[ln15+16*nt]; }
        #pragma unroll
        for (int mt = 0; mt < 2; ++mt) {
            #pragma unroll
            for (int reg = 0; reg < 4; ++reg) {
                float s = 0.f, sq = 0.f;
                #pragma unroll
                for (int nt = 0; nt < 8; ++nt) { float v = acc2[mt][nt][reg]; s += v; sq += v*v; }
                #pragma unroll
                for (int m = 1; m < 16; m <<= 1) { s += __shfl_xor(s, m); sq += __shfl_xor(sq, m); }
                const float mean = s * (1.f/HID);
                const float var  = sq * (1.f/HID) - mean*mean;
                const float rstd = rsqrtf(fmaxf(var, 0.f) + EPS);
                #pragma unroll
                for (int nt = 0; nt < 8; ++nt)
                    acc2[mt][nt][reg] = (acc2[mt][nt][reg] - mean)*rstd*gv[nt] + bv[nt];
            }
        }
    }

    // ---- final: gelu(h + LN2), max over rows, store ----
    #pragma unroll
    for (int nt = 0; nt < 8; ++nt) {
        float m0 = -INFINITY;
        m0 = fmaxf(m0, gelu_fast(bf2f((unsigned short)hp0[nt][0])         + acc2[0][nt][0]));
        m0 = fmaxf(m0, gelu_fast(bf2f((unsigned short)(hp0[nt][0] >> 16)) + acc2[0][nt][1]));
        m0 = fmaxf(m0, gelu_fast(bf2f((unsigned short)hp0[nt][1])         + acc2[0][nt][2]));
        m0 = fmaxf(m0, gelu_fast(bf2f((unsigned short)(hp0[nt][1] >> 16)) + acc2[0][nt][3]));
        if (q == 0) {
            m0 = fmaxf(m0, gelu_fast(bf2f((unsigned short)hp1[nt][0])         + acc2[1][nt][0]));
            m0 = fmaxf(m0, gelu_fast(bf2f((unsigned short)(hp1[nt][0] >> 16)) + acc2[1][nt][1]));
            m0 = fmaxf(m0, gelu_fast(bf2f((unsigned short)hp1[nt][1])         + acc2[1][nt][2]));
            m0 = fmaxf(m0, gelu_fast(bf2f((unsigned short)(hp1[nt][1] >> 16)) + acc2[1][nt][3]));
        }
        m0 = fmaxf(m0, __shfl_xor(m0, 16));
        m0 = fmaxf(m0, __shfl_xor(m0, 32));
        if (l < 16) out[(size_t)item*HID + 16*nt + l] = m0;
    }
}

extern "C" void kernel_launch(void* const* d_in, const int* in_sizes, int n_in,
                              void* d_out, int out_size, void* d_ws, size_t ws_size,
                              hipStream_t stream) {
    (void)n_in; (void)out_size; (void)ws_size;
    const float* x       = (const float*)d_in[0];
    const float* w_embed = (const float*)d_in[1];
    const float* b_embed = (const float*)d_in[2];
    const float* w1      = (const float*)d_in[3];
    const float* b1      = (const float*)d_in[4];
    const float* w2      = (const float*)d_in[5];
    const float* b2      = (const float*)d_in[6];
    const float* g1      = (const float*)d_in[7];
    const float* be1     = (const float*)d_in[8];
    const float* g2      = (const float*)d_in[9];
    const float* be2     = (const float*)d_in[10];
    float* out = (float*)d_out;

    // ws layout: [c1f 512B][wswM1 8192B][wsw2 32768B]
    unsigned char* ws = (unsigned char*)d_ws;
    float* c1f            = (float*)(ws + 0);
    unsigned short* wswM1 = (unsigned short*)(ws + 512);
    unsigned short* wsw2  = (unsigned short*)(ws + 512 + 8192);

    const int nItems  = in_sizes[0] / (N_NODES * IN_DIM);
    const int nBlocks = (nItems + IPB - 1) / IPB;

    prep_all<<<dim3(81), dim3(256), 0, stream>>>(w_embed, b_embed, w1, b1, w2,
                                                 wswM1, wsw2, c1f);
    hbond_main<<<dim3(nBlocks), dim3(256), 0, stream>>>(
        x, c1f, b2, g1, be1, g2, be2, wswM1, wsw2, out, nItems);
}

// Round 9
// 323.211 us; speedup vs baseline: 1.2456x; 1.1008x over previous
//
#include <hip/hip_runtime.h>
#include <math.h>

#define N_NODES 20
#define IN_DIM  9
#define HID     128
#define K_NBR   5
#define EPS     1e-5f
#define IPB     4          // items (waves) per 256-thread block

// ---- per-item LDS slice (bytes), regions with disjoint lifetimes alias at 0 ----
// phase A: xs (180 f32 = 720B @0) + adjx (20x16 bf16 = 640B @736)
// phase B: hrm  (20 rows x 136 bf16 = 5440B @0)   h row-major, A-operand for t=h@W2
// phase C: tT   (128 cols x 24 bf16 = 6144B @0)   t transposed, B-operand for adj@t
// guard   : 16B zeros @6144 (col127/q3 B-frag overread target; never clobbered)
// hsideT  : h rows 16..19 transposed [col][4] = 1024B @6160 (persists to final;
//           replaces the hp1 register carry that caused r7/r8 scratch spills)
#define ADJX_OFF  736
#define HSIDE_OFF 6160
#define SLICE     7184
#define HTSTR     24       // tT row-slots per col (multiple of 8 -> b128-aligned reads)
#define HRSTR     136      // hrm row stride (272B: 16B-mult, 4 mod 32 banks -> 2-way free)

typedef __attribute__((ext_vector_type(8))) short short8;   // 8 bf16 (4 VGPRs)
typedef __attribute__((ext_vector_type(4))) float f32x4;    // MFMA C/D frag
typedef __attribute__((ext_vector_type(2))) unsigned int u32x2;
typedef __attribute__((ext_vector_type(4))) unsigned int u32x4;

#define WB() __builtin_amdgcn_wave_barrier()

__device__ __forceinline__ unsigned short f2bf(float f) {
    unsigned u = __builtin_bit_cast(unsigned, f);
    u += 0x7fffu + ((u >> 16) & 1u);          // RNE
    return (unsigned short)(u >> 16);
}
#if __has_builtin(__builtin_amdgcn_cvt_pk_bf16_f32)
typedef __attribute__((ext_vector_type(2))) __bf16 bf16x2;
__device__ __forceinline__ unsigned cvtpk(float a, float b) {   // low=bf16(a), hi=bf16(b)
    bf16x2 r = __builtin_amdgcn_cvt_pk_bf16_f32(a, b);
    return __builtin_bit_cast(unsigned, r);
}
#else
__device__ __forceinline__ unsigned cvtpk(float a, float b) {
    return (unsigned)f2bf(a) | ((unsigned)f2bf(b) << 16);
}
#endif
__device__ __forceinline__ float bf2f(unsigned short h) {
    return __builtin_bit_cast(float, (unsigned)h << 16);
}
// tanh-form GELU (|err| <~1e-3): x*u/(u+1), u=e^{2*0.79788456*(x+0.044715x^3)}
__device__ __forceinline__ float gelu_fast(float x) {
    float x2 = x * x;
    float y  = x * fmaf(x2, 0.07135806592f, 1.5957691216f);
    float u  = __expf(fminf(y, 60.0f));
    return x * u * __builtin_amdgcn_rcpf(u + 1.0f);
}

__device__ __forceinline__ f32x4 mfma16(short8 a, short8 b, f32x4 c) {
    return __builtin_amdgcn_mfma_f32_16x16x32_bf16(a, b, c, 0, 0, 0);
}

// ===== single prep kernel (no inter-kernel deps, fully parallel) =====
// wswM1[nt*512 + lane*8 + j] = bf16(M1[k][n]), M1 = We@W1 (9x128), k=(lane>>4)*8+j (0 if k>=9),
//                              n = nt*16 + (lane&15)
// wsw2 [(ks*8+nt)*512 + lane*8 + j] = bf16(w2[k][n]), k=ks*32+(lane>>4)*8+j
// c1f[n] = 5*(be@W1)[n] + b1[n]
__global__ void prep_all(const float* __restrict__ w_embed, const float* __restrict__ b_embed,
                         const float* __restrict__ w1, const float* __restrict__ b1,
                         const float* __restrict__ w2,
                         unsigned short* __restrict__ wswM1, unsigned short* __restrict__ wsw2,
                         float* __restrict__ c1f) {
    int idx = blockIdx.x * 256 + threadIdx.x;          // 20608 total
    if (idx < 4096) {
        int j = idx & 7, lane = (idx >> 3) & 63, nt = (idx >> 9) & 7;
        int k = (lane >> 4) * 8 + j;
        int n = nt * 16 + (lane & 15);
        unsigned short r = 0;
        if (k < IN_DIM) {
            float acc = 0.f;
            for (int c = 0; c < HID; ++c)
                acc = fmaf(w_embed[k*HID + c], w1[c*HID + n], acc);
            r = f2bf(acc);
        }
        wswM1[idx] = r;
    } else if (idx < 4096 + 16384) {
        int i2 = idx - 4096;
        int j = i2 & 7, lane = (i2 >> 3) & 63, nt = (i2 >> 9) & 7, ks = (i2 >> 12) & 3;
        int k = ks * 32 + (lane >> 4) * 8 + j;
        int n = nt * 16 + (lane & 15);
        wsw2[i2] = f2bf(w2[k*HID + n]);
    } else if (idx < 4096 + 16384 + 128) {
        int n = idx - (4096 + 16384);
        float cb = 0.f;
        for (int c = 0; c < HID; ++c)
            cb = fmaf(b_embed[c], w1[c*HID + n], cb);
        c1f[n] = 5.0f * cb + b1[n];
    }
}

// ===== main =====
// launch_bounds (256,3): ~170 unified VGPR cap. Peak live ~108 regs (hp1 carry
// removed -> r7/r8's scratch spills gone); actual usage <=128 -> 4 waves/SIMD.
__global__ __launch_bounds__(256, 3) void hbond_main(
    const float* __restrict__ x_in,
    const float* __restrict__ c1f, const float* __restrict__ b2,
    const float* __restrict__ g1, const float* __restrict__ be1,
    const float* __restrict__ g2, const float* __restrict__ be2,
    const unsigned short* __restrict__ wswM1, const unsigned short* __restrict__ wsw2,
    float* __restrict__ out, int nItems)
{
    __shared__ __align__(16) unsigned char smem[IPB * SLICE];

    const int l  = threadIdx.x & 63;
    const int wv = threadIdx.x >> 6;
    const int item = blockIdx.x * IPB + wv;
    if (item >= nItems) return;               // wave-uniform; no cross-wave barriers

    unsigned char* slice = smem + wv * SLICE;
    float*          xs     = (float*)(slice);                    // phase A
    unsigned short* adjx   = (unsigned short*)(slice + ADJX_OFF);// phase A
    unsigned short* hrm    = (unsigned short*)(slice);           // phase B (aliases A)
    unsigned short* tT     = (unsigned short*)(slice);           // phase C (aliases B)
    unsigned short* hsideT = (unsigned short*)(slice + HSIDE_OFF); // h rows16..19, [col][4]

    const int ln15 = l & 15, q = l >> 4;
    const float* xb = x_in + (size_t)item * (N_NODES * IN_DIM);

    // guard for tT col127/q3 overread (bytes 6144..6160); hrm/tT stay below it
    if (l == 0) *(u32x4*)(slice + HTSTR * HID * 2) = (u32x4){0,0,0,0};

    // ---- stage x: 180 floats ----
    if (l < 45) ((float4*)xs)[l] = ((const float4*)xb)[l];
    WB();

    // ---- KNN: lane r = row r (r<20); bit-safe d2; tie -> lower index ----
    unsigned nbrp = 0;                        // 5 x 5-bit neighbor indices
    {
        const int rsel = (l < N_NODES) ? l : 0;
        const float px = xs[rsel*IN_DIM+6], py = xs[rsel*IN_DIM+7], pz = xs[rsel*IN_DIM+8];
        float d2[N_NODES];
        #pragma unroll
        for (int j = 0; j < N_NODES; ++j) {
            float dx = __fsub_rn(px, __shfl(px, j));
            float dy = __fsub_rn(py, __shfl(py, j));
            float dz = __fsub_rn(pz, __shfl(pz, j));
            d2[j] = __fadd_rn(__fadd_rn(__fmul_rn(dx,dx), __fmul_rn(dy,dy)), __fmul_rn(dz,dz));
        }
        unsigned used = 0u;
        #pragma unroll
        for (int k = 0; k < K_NBR; ++k) {
            float best = INFINITY; int bi = 0;
            #pragma unroll
            for (int j = 0; j < N_NODES; ++j) {
                bool take = (!((used >> j) & 1u)) && (d2[j] < best);
                best = take ? d2[j] : best;
                bi   = take ? j     : bi;
            }
            used |= (1u << bi);
            nbrp |= (unsigned)bi << (5*k);
        }
    }

    // ---- adjacency bitmask + bf16 A-fragments (k=q*8+j; bits >=20 always 0) ----
    unsigned amask = 0;
    #pragma unroll
    for (int j = 0; j < K_NBR; ++j) amask |= 1u << ((nbrp >> (5*j)) & 31);
    const unsigned am0 = (unsigned)__shfl((int)amask, ln15);
    const unsigned am1 = (unsigned)__shfl((int)amask, ln15 + 16); // rows>=20: garbage, discarded
    short8 adjf0, adjf1;
    #pragma unroll
    for (int j = 0; j < 8; ++j) {
        adjf0[j] = (short)(((am0 >> (q*8 + j)) & 1u) ? 0x3F80 : 0);
        adjf1[j] = (short)(((am1 >> (q*8 + j)) & 1u) ? 0x3F80 : 0);
    }

    // ---- agg1 on raw x (fp32 exact): adjx[r][c] = sum_{5 nbrs} x[nj][c] ----
    if (l < N_NODES) {
        float s[IN_DIM];
        #pragma unroll
        for (int c = 0; c < IN_DIM; ++c) s[c] = 0.f;
        #pragma unroll
        for (int j = 0; j < K_NBR; ++j) {
            const int nj = (nbrp >> (5*j)) & 31;
            #pragma unroll
            for (int c = 0; c < IN_DIM; ++c) s[c] += xs[nj*IN_DIM + c];
        }
        u32x4 p0 = { cvtpk(s[0],s[1]), cvtpk(s[2],s[3]), cvtpk(s[4],s[5]), cvtpk(s[6],s[7]) };
        u32x4 p1 = { cvtpk(s[8],0.f), 0, 0, 0 };
        *(u32x4*)&adjx[l*16 + 0] = p0;
        *(u32x4*)&adjx[l*16 + 8] = p1;
    }
    WB();

    f32x4 acc[2][8];
    const int rlo = ln15, rhi = (ln15 + 16 > 19) ? 19 : ln15 + 16;  // clamp garbage rows

    // ---- GEMM1: y1 = adjx @ M1 + c1  (K=32, 16 MFMA; B zero for k>=9) ----
    {
        const short8 a0 = *(const short8*)&adjx[rlo*16 + (q & 1)*8];
        const short8 a1 = *(const short8*)&adjx[rhi*16 + (q & 1)*8];
        #pragma unroll
        for (int nt = 0; nt < 8; ++nt) {
            const float bv = c1f[ln15 + 16*nt];
            f32x4 c0 = (f32x4){bv, bv, bv, bv};
            const short8 bfr = *(const short8*)&wswM1[nt*512 + l*8];
            acc[0][nt] = mfma16(a0, bfr, c0);
            acc[1][nt] = mfma16(a1, bfr, c0);
        }
    }

    // ---- LN1 + GELU (C-layout regs) -> h ----
    {
        float gv[8], bv[8];
        #pragma unroll
        for (int nt = 0; nt < 8; ++nt) { gv[nt] = g1[ln15+16*nt]; bv[nt] = be1[ln15+16*nt]; }
        #pragma unroll
        for (int mt = 0; mt < 2; ++mt) {
            #pragma unroll
            for (int reg = 0; reg < 4; ++reg) {
                float s = 0.f, sq = 0.f;
                #pragma unroll
                for (int nt = 0; nt < 8; ++nt) { float v = acc[mt][nt][reg]; s += v; sq += v*v; }
                #pragma unroll
                for (int m = 1; m < 16; m <<= 1) { s += __shfl_xor(s, m); sq += __shfl_xor(sq, m); }
                const float mean = s * (1.f/HID);
                const float var  = sq * (1.f/HID) - mean*mean;
                const float rstd = rsqrtf(fmaxf(var, 0.f) + EPS);
                #pragma unroll
                for (int nt = 0; nt < 8; ++nt)
                    acc[mt][nt][reg] = gelu_fast((acc[mt][nt][reg] - mean)*rstd*gv[nt] + bv[nt]);
            }
        }
    }

    // ---- residual: rows 0..15 packed in 16 regs; rows 16..19 go to hsideT (LDS) ----
    unsigned hp0[8][2];
    #pragma unroll
    for (int nt = 0; nt < 8; ++nt) {
        hp0[nt][0] = cvtpk(acc[0][nt][0], acc[0][nt][1]);
        hp0[nt][1] = cvtpk(acc[0][nt][2], acc[0][nt][3]);
    }
    WB();   // adjx/xs dead; GEMM1 A-reads complete

    // ---- scatter h (C-layout) -> hrm row-major; q==0 also writes hsideT ----
    #pragma unroll
    for (int nt = 0; nt < 8; ++nt) {
        const int col = ln15 + 16*nt;
        hrm[(q*4+0)*HRSTR + col] = (unsigned short)hp0[nt][0];
        hrm[(q*4+1)*HRSTR + col] = (unsigned short)(hp0[nt][0] >> 16);
        hrm[(q*4+2)*HRSTR + col] = (unsigned short)hp0[nt][1];
        hrm[(q*4+3)*HRSTR + col] = (unsigned short)(hp0[nt][1] >> 16);
        if (q == 0) {
            unsigned v01 = cvtpk(acc[1][nt][0], acc[1][nt][1]);
            unsigned v23 = cvtpk(acc[1][nt][2], acc[1][nt][3]);
            hrm[16*HRSTR + col] = (unsigned short)v01;
            hrm[17*HRSTR + col] = (unsigned short)(v01 >> 16);
            hrm[18*HRSTR + col] = (unsigned short)v23;
            hrm[19*HRSTR + col] = (unsigned short)(v23 >> 16);
            *(u32x2*)&hsideT[col*4] = (u32x2){v01, v23};   // [col][rows16..19]
        }
    }
    WB();

    // ---- GEMM2': t = h @ W2  (K=128, 64 MFMA; garbage rows clamped) ----
    #pragma unroll
    for (int nt = 0; nt < 8; ++nt) { acc[0][nt] = (f32x4){0,0,0,0}; acc[1][nt] = acc[0][nt]; }
    #pragma unroll
    for (int ks = 0; ks < 4; ++ks) {
        const short8 a0 = *(const short8*)&hrm[rlo*HRSTR + ks*32 + q*8];
        const short8 a1 = *(const short8*)&hrm[rhi*HRSTR + ks*32 + q*8];
        #pragma unroll
        for (int nt = 0; nt < 8; ++nt) {
            const short8 bfr = *(const short8*)&wsw2[(ks*8 + nt)*512 + l*8];
            acc[0][nt] = mfma16(a0, bfr, acc[0][nt]);
            acc[1][nt] = mfma16(a1, bfr, acc[1][nt]);
        }
    }
    WB();   // all hrm reads complete; tT may overwrite

    // ---- store t transposed: tT[col][row] (cheap u32x2 stores) ----
    #pragma unroll
    for (int nt = 0; nt < 8; ++nt) {
        const int col = ln15 + 16*nt;
        u32x2 w0 = { cvtpk(acc[0][nt][0], acc[0][nt][1]), cvtpk(acc[0][nt][2], acc[0][nt][3]) };
        *(u32x2*)&tT[col*HTSTR + q*4] = w0;                        // rows q*4..q*4+3
        if (q == 0) {
            u32x2 w1v = { cvtpk(acc[1][nt][0], acc[1][nt][1]), cvtpk(acc[1][nt][2], acc[1][nt][3]) };
            *(u32x2*)&tT[col*HTSTR + 16] = w1v;                    // rows 16..19
        }
    }
    // zero row-slots 20..23 for every col (lane covers col l and col l+64).
    // REQUIRED even though adjacency A-bits >=20 are zero: stale bytes can
    // encode bf16 Inf/NaN and IEEE 0*Inf = NaN would poison the MFMA dot.
    *(u32x2*)&tT[l*HTSTR + 20]        = (u32x2){0,0};
    *(u32x2*)&tT[(l + 64)*HTSTR + 20] = (u32x2){0,0};
    WB();

    // ---- y2 = adj @ t + b2  (16 MFMA) ----
    f32x4 acc2[2][8];
    #pragma unroll
    for (int nt = 0; nt < 8; ++nt) {
        const float bv = b2[ln15 + 16*nt];
        f32x4 c0 = (f32x4){bv, bv, bv, bv};
        const short8 bfr = *(const short8*)&tT[(ln15 + 16*nt)*HTSTR + q*8];  // k=q*8+j
        acc2[0][nt] = mfma16(adjf0, bfr, c0);
        acc2[1][nt] = mfma16(adjf1, bfr, c0);
    }

    // ---- LN2 ----
    {
        float gv[8], bv[8];
        #pragma unroll
        for (int nt = 0; nt < 8; ++nt) { gv[nt] = g2[ln15+16*nt]; bv[nt] = be2[ln15+16*nt]; }
        #pragma unroll
        for (int mt = 0; mt < 2; ++mt) {
            #pragma unroll
            for (int reg = 0; reg < 4; ++reg) {
                float s = 0.f, sq = 0.f;
                #pragma unroll
                for (int nt = 0; nt < 8; ++nt) { float v = acc2[mt][nt][reg]; s += v; sq += v*v; }
                #pragma unroll
                for (int m = 1; m < 16; m <<= 1) { s += __shfl_xor(s, m); sq += __shfl_xor(sq, m); }
                const float mean = s * (1.f/HID);
                const float var  = sq * (1.f/HID) - mean*mean;
                const float rstd = rsqrtf(fmaxf(var, 0.f) + EPS);
                #pragma unroll
                for (int nt = 0; nt < 8; ++nt)
                    acc2[mt][nt][reg] = (acc2[mt][nt][reg] - mean)*rstd*gv[nt] + bv[nt];
            }
        }
    }

    // ---- final: gelu(h + LN2), max over rows, store ----
    #pragma unroll
    for (int nt = 0; nt < 8; ++nt) {
        float m0 = -INFINITY;
        m0 = fmaxf(m0, gelu_fast(bf2f((unsigned short)hp0[nt][0])         + acc2[0][nt][0]));
        m0 = fmaxf(m0, gelu_fast(bf2f((unsigned short)(hp0[nt][0] >> 16)) + acc2[0][nt][1]));
        m0 = fmaxf(m0, gelu_fast(bf2f((unsigned short)hp0[nt][1])         + acc2[0][nt][2]));
        m0 = fmaxf(m0, gelu_fast(bf2f((unsigned short)(hp0[nt][1] >> 16)) + acc2[0][nt][3]));
        if (q == 0) {
            const int col = ln15 + 16*nt;
            const ushort4 hw = *(const ushort4*)&hsideT[col*4];    // rows 16..19
            m0 = fmaxf(m0, gelu_fast(bf2f(hw.x) + acc2[1][nt][0]));
            m0 = fmaxf(m0, gelu_fast(bf2f(hw.y) + acc2[1][nt][1]));
            m0 = fmaxf(m0, gelu_fast(bf2f(hw.z) + acc2[1][nt][2]));
            m0 = fmaxf(m0, gelu_fast(bf2f(hw.w) + acc2[1][nt][3]));
        }
        m0 = fmaxf(m0, __shfl_xor(m0, 16));
        m0 = fmaxf(m0, __shfl_xor(m0, 32));
        if (l < 16) out[(size_t)item*HID + 16*nt + l] = m0;
    }
}

extern "C" void kernel_launch(void* const* d_in, const int* in_sizes, int n_in,
                              void* d_out, int out_size, void* d_ws, size_t ws_size,
                              hipStream_t stream) {
    (void)n_in; (void)out_size; (void)ws_size;
    const float* x       = (const float*)d_in[0];
    const float* w_embed = (const float*)d_in[1];
    const float* b_embed = (const float*)d_in[2];
    const float* w1      = (const float*)d_in[3];
    const float* b1      = (const float*)d_in[4];
    const float* w2      = (const float*)d_in[5];
    const float* b2      = (const float*)d_in[6];
    const float* g1      = (const float*)d_in[7];
    const float* be1     = (const float*)d_in[8];
    const float* g2      = (const float*)d_in[9];
    const float* be2     = (const float*)d_in[10];
    float* out = (float*)d_out;

    // ws layout: [c1f 512B][wswM1 8192B][wsw2 32768B]
    unsigned char* ws = (unsigned char*)d_ws;
    float* c1f            = (float*)(ws + 0);
    unsigned short* wswM1 = (unsigned short*)(ws + 512);
    unsigned short* wsw2  = (unsigned short*)(ws + 512 + 8192);

    const int nItems  = in_sizes[0] / (N_NODES * IN_DIM);
    const int nBlocks = (nItems + IPB - 1) / IPB;

    prep_all<<<dim3(81), dim3(256), 0, stream>>>(w_embed, b_embed, w1, b1, w2,
                                                 wswM1, wsw2, c1f);
    hbond_main<<<dim3(nBlocks), dim3(256), 0, stream>>>(
        x, c1f, b2, g1, be1, g2, be2, wswM1, wsw2, out, nItems);
}

// Round 10
// 299.269 us; speedup vs baseline: 1.3452x; 1.0800x over previous
//
#include <hip/hip_runtime.h>
#include <math.h>

#define N_NODES 20
#define IN_DIM  9
#define HID     128
#define K_NBR   5
#define EPS     1e-5f
#define IPB     2          // items (waves) per 128-thread block

// ---- per-item LDS slice (bytes), regions with disjoint lifetimes alias at 0 ----
// phase A: xs (180 f32 = 720B @0) + adjx (20x16 bf16 = 640B @736)
// phase B: hrm (20 rows x 136 bf16 = 5440B @0)   h row-major, A-operand for t=h@W2
// phase C: tT  (128 cols x 24 bf16 = 6144B @0)   t transposed, B-operand for adj@t
// guard  : 16B zeros @6144 (col127/q3 B-frag overread target; never clobbered)
// hT     : h transposed [128 cols][20 rows] = 5120B @6160 (persists to final;
//          replaces the 16-reg hp0 carry -> unified regs 144->~128, 4 waves/SIMD)
#define ADJX_OFF  736
#define HT_OFF    6160
#define SLICE     11280
#define HTSTR     24       // tT row-slots per col (multiple of 8 -> b128-aligned reads)
#define HRSTR     136      // hrm row stride (272B: 16B-mult, 4 mod 32 banks -> 2-way free)
#define HTF       20       // hT row-slots per col (40B stride, 8B-aligned b64 accesses)

typedef __attribute__((ext_vector_type(8))) short short8;   // 8 bf16 (4 VGPRs)
typedef __attribute__((ext_vector_type(4))) float f32x4;    // MFMA C/D frag
typedef __attribute__((ext_vector_type(2))) unsigned int u32x2;
typedef __attribute__((ext_vector_type(4))) unsigned int u32x4;

#define WB() __builtin_amdgcn_wave_barrier()

__device__ __forceinline__ unsigned short f2bf(float f) {
    unsigned u = __builtin_bit_cast(unsigned, f);
    u += 0x7fffu + ((u >> 16) & 1u);          // RNE
    return (unsigned short)(u >> 16);
}
#if __has_builtin(__builtin_amdgcn_cvt_pk_bf16_f32)
typedef __attribute__((ext_vector_type(2))) __bf16 bf16x2;
__device__ __forceinline__ unsigned cvtpk(float a, float b) {   // low=bf16(a), hi=bf16(b)
    bf16x2 r = __builtin_amdgcn_cvt_pk_bf16_f32(a, b);
    return __builtin_bit_cast(unsigned, r);
}
#else
__device__ __forceinline__ unsigned cvtpk(float a, float b) {
    return (unsigned)f2bf(a) | ((unsigned)f2bf(b) << 16);
}
#endif
__device__ __forceinline__ float bf2f(unsigned short h) {
    return __builtin_bit_cast(float, (unsigned)h << 16);
}
// tanh-form GELU (|err| <~1e-3): x*u/(u+1), u=e^{2*0.79788456*(x+0.044715x^3)}
// Unimodal (single minimum near x=-0.75): max over a set = max(gelu(min), gelu(max)).
__device__ __forceinline__ float gelu_fast(float x) {
    float x2 = x * x;
    float y  = x * fmaf(x2, 0.07135806592f, 1.5957691216f);
    float u  = __expf(fminf(y, 60.0f));
    return x * u * __builtin_amdgcn_rcpf(u + 1.0f);
}

__device__ __forceinline__ f32x4 mfma16(short8 a, short8 b, f32x4 c) {
    return __builtin_amdgcn_mfma_f32_16x16x32_bf16(a, b, c, 0, 0, 0);
}

// ===== single prep kernel, fully parallel (r9's 16-CU serial dots cost ~30us) =====
// tid [0,16384): M1=We@W1 swizzled -> wswM1; 4 threads per output, 32-chunk dots
// tid [16384,16896): c1 = 5*(be@W1)+b1; 4 threads per output
// tid [16896,33280): wsw2 swizzle of w2
__global__ void prep_all(const float* __restrict__ w_embed, const float* __restrict__ b_embed,
                         const float* __restrict__ w1, const float* __restrict__ b1,
                         const float* __restrict__ w2,
                         unsigned short* __restrict__ wswM1, unsigned short* __restrict__ wsw2,
                         float* __restrict__ c1f) {
    int tid = blockIdx.x * 256 + threadIdx.x;          // 33280 total -> 130 blocks
    if (tid < 16384) {
        int oid = tid >> 2, sub = tid & 3;
        int j = oid & 7, lane = (oid >> 3) & 63, nt = (oid >> 9) & 7;
        int k = (lane >> 4) * 8 + j;
        int n = nt * 16 + (lane & 15);
        float acc = 0.f;
        if (k < IN_DIM) {
            #pragma unroll 8
            for (int c = sub * 32; c < sub * 32 + 32; ++c)
                acc = fmaf(w_embed[k*HID + c], w1[c*HID + n], acc);
        }
        acc += __shfl_xor(acc, 1);
        acc += __shfl_xor(acc, 2);
        if (sub == 0) wswM1[oid] = (k < IN_DIM) ? f2bf(acc) : (unsigned short)0;
    } else if (tid < 16896) {
        int t2 = tid - 16384;
        int n = t2 >> 2, sub = t2 & 3;
        float cb = 0.f;
        #pragma unroll 8
        for (int c = sub * 32; c < sub * 32 + 32; ++c)
            cb = fmaf(b_embed[c], w1[c*HID + n], cb);
        cb += __shfl_xor(cb, 1);
        cb += __shfl_xor(cb, 2);
        if (sub == 0) c1f[n] = 5.0f * cb + b1[n];
    } else if (tid < 33280) {
        int i2 = tid - 16896;
        int j = i2 & 7, lane = (i2 >> 3) & 63, nt = (i2 >> 9) & 7, ks = (i2 >> 12) & 3;
        int k = ks * 32 + (lane >> 4) * 8 + j;
        int n = nt * 16 + (lane & 15);
        wsw2[i2] = f2bf(w2[k*HID + n]);
    }
}

// ===== main =====
// (128,3): ~170-reg cap (no forced spill); target natural usage ~64 arch + 64 acc
// = 128 unified -> 4 waves/SIMD. LDS 22560B/block -> 7 blocks/CU -> 14 waves.
__global__ __launch_bounds__(128, 3) void hbond_main(
    const float* __restrict__ x_in,
    const float* __restrict__ c1f, const float* __restrict__ b2,
    const float* __restrict__ g1, const float* __restrict__ be1,
    const float* __restrict__ g2, const float* __restrict__ be2,
    const unsigned short* __restrict__ wswM1, const unsigned short* __restrict__ wsw2,
    float* __restrict__ out, int nItems)
{
    __shared__ __align__(16) unsigned char smem[IPB * SLICE];

    const int l  = threadIdx.x & 63;
    const int wv = threadIdx.x >> 6;
    const int item = blockIdx.x * IPB + wv;
    if (item >= nItems) return;               // wave-uniform; no cross-wave barriers

    unsigned char* slice = smem + wv * SLICE;
    float*          xs   = (float*)(slice);                    // phase A
    unsigned short* adjx = (unsigned short*)(slice + ADJX_OFF);// phase A
    unsigned short* hrm  = (unsigned short*)(slice);           // phase B (aliases A)
    unsigned short* tT   = (unsigned short*)(slice);           // phase C (aliases B)
    unsigned short* hT   = (unsigned short*)(slice + HT_OFF);  // h residual, [col][20]

    const int ln15 = l & 15, q = l >> 4;
    const float* xb = x_in + (size_t)item * (N_NODES * IN_DIM);

    // guard for tT col127/q3 overread (bytes 6144..6160); hrm/tT stay below, hT above
    if (l == 0) *(u32x4*)(slice + HTSTR * HID * 2) = (u32x4){0,0,0,0};

    // ---- stage x: 180 floats ----
    if (l < 45) ((float4*)xs)[l] = ((const float4*)xb)[l];
    WB();

    // ---- KNN: lane r = row r (r<20); bit-safe d2; tie -> lower index ----
    unsigned nbrp = 0;                        // 5 x 5-bit neighbor indices
    {
        const int rsel = (l < N_NODES) ? l : 0;
        const float px = xs[rsel*IN_DIM+6], py = xs[rsel*IN_DIM+7], pz = xs[rsel*IN_DIM+8];
        float d2[N_NODES];
        #pragma unroll
        for (int j = 0; j < N_NODES; ++j) {
            float dx = __fsub_rn(px, __shfl(px, j));
            float dy = __fsub_rn(py, __shfl(py, j));
            float dz = __fsub_rn(pz, __shfl(pz, j));
            d2[j] = __fadd_rn(__fadd_rn(__fmul_rn(dx,dx), __fmul_rn(dy,dy)), __fmul_rn(dz,dz));
        }
        unsigned used = 0u;
        #pragma unroll
        for (int k = 0; k < K_NBR; ++k) {
            float best = INFINITY; int bi = 0;
            #pragma unroll
            for (int j = 0; j < N_NODES; ++j) {
                bool take = (!((used >> j) & 1u)) && (d2[j] < best);
                best = take ? d2[j] : best;
                bi   = take ? j     : bi;
            }
            used |= (1u << bi);
            nbrp |= (unsigned)bi << (5*k);
        }
    }

    // ---- adjacency bitmask + bf16 A-fragments (k=q*8+j; bits >=20 always 0) ----
    unsigned amask = 0;
    #pragma unroll
    for (int j = 0; j < K_NBR; ++j) amask |= 1u << ((nbrp >> (5*j)) & 31);
    const unsigned am0 = (unsigned)__shfl((int)amask, ln15);
    const unsigned am1 = (unsigned)__shfl((int)amask, ln15 + 16); // rows>=20: garbage, discarded
    short8 adjf0, adjf1;
    #pragma unroll
    for (int j = 0; j < 8; ++j) {
        adjf0[j] = (short)(((am0 >> (q*8 + j)) & 1u) ? 0x3F80 : 0);
        adjf1[j] = (short)(((am1 >> (q*8 + j)) & 1u) ? 0x3F80 : 0);
    }

    // ---- agg1 on raw x (fp32 exact): adjx[r][c] = sum_{5 nbrs} x[nj][c] ----
    if (l < N_NODES) {
        float s[IN_DIM];
        #pragma unroll
        for (int c = 0; c < IN_DIM; ++c) s[c] = 0.f;
        #pragma unroll
        for (int j = 0; j < K_NBR; ++j) {
            const int nj = (nbrp >> (5*j)) & 31;
            #pragma unroll
            for (int c = 0; c < IN_DIM; ++c) s[c] += xs[nj*IN_DIM + c];
        }
        u32x4 p0 = { cvtpk(s[0],s[1]), cvtpk(s[2],s[3]), cvtpk(s[4],s[5]), cvtpk(s[6],s[7]) };
        u32x4 p1 = { cvtpk(s[8],0.f), 0, 0, 0 };
        *(u32x4*)&adjx[l*16 + 0] = p0;
        *(u32x4*)&adjx[l*16 + 8] = p1;
    }
    WB();

    f32x4 acc[2][8];
    const int rlo = ln15, rhi = (ln15 + 16 > 19) ? 19 : ln15 + 16;  // clamp garbage rows

    // ---- GEMM1: y1 = adjx @ M1 + c1  (K=32, 16 MFMA; B zero for k>=9) ----
    {
        const short8 a0 = *(const short8*)&adjx[rlo*16 + (q & 1)*8];
        const short8 a1 = *(const short8*)&adjx[rhi*16 + (q & 1)*8];
        #pragma unroll
        for (int nt = 0; nt < 8; ++nt) {
            const float bv = c1f[ln15 + 16*nt];
            f32x4 c0 = (f32x4){bv, bv, bv, bv};
            const short8 bfr = *(const short8*)&wswM1[nt*512 + l*8];
            acc[0][nt] = mfma16(a0, bfr, c0);
            acc[1][nt] = mfma16(a1, bfr, c0);
        }
    }

    // ---- LN1 + GELU (C-layout regs) -> h ----
    {
        float gv[8], bv[8];
        #pragma unroll
        for (int nt = 0; nt < 8; ++nt) { gv[nt] = g1[ln15+16*nt]; bv[nt] = be1[ln15+16*nt]; }
        #pragma unroll
        for (int mt = 0; mt < 2; ++mt) {
            #pragma unroll
            for (int reg = 0; reg < 4; ++reg) {
                float s = 0.f, sq = 0.f;
                #pragma unroll
                for (int nt = 0; nt < 8; ++nt) { float v = acc[mt][nt][reg]; s += v; sq += v*v; }
                #pragma unroll
                for (int m = 1; m < 16; m <<= 1) { s += __shfl_xor(s, m); sq += __shfl_xor(sq, m); }
                const float mean = s * (1.f/HID);
                const float var  = sq * (1.f/HID) - mean*mean;
                const float rstd = rsqrtf(fmaxf(var, 0.f) + EPS);
                #pragma unroll
                for (int nt = 0; nt < 8; ++nt)
                    acc[mt][nt][reg] = gelu_fast((acc[mt][nt][reg] - mean)*rstd*gv[nt] + bv[nt]);
            }
        }
    }
    WB();   // adjx/xs dead; GEMM1 A-reads complete

    // ---- scatter h: hrm row-major (GEMM2' A-operand) + hT transposed (residual) ----
    #pragma unroll
    for (int nt = 0; nt < 8; ++nt) {
        const int col = ln15 + 16*nt;
        unsigned u01 = cvtpk(acc[0][nt][0], acc[0][nt][1]);
        unsigned u23 = cvtpk(acc[0][nt][2], acc[0][nt][3]);
        hrm[(q*4+0)*HRSTR + col] = (unsigned short)u01;
        hrm[(q*4+1)*HRSTR + col] = (unsigned short)(u01 >> 16);
        hrm[(q*4+2)*HRSTR + col] = (unsigned short)u23;
        hrm[(q*4+3)*HRSTR + col] = (unsigned short)(u23 >> 16);
        *(u32x2*)&hT[col*HTF + q*4] = (u32x2){u01, u23};
        if (q == 0) {
            unsigned v01 = cvtpk(acc[1][nt][0], acc[1][nt][1]);
            unsigned v23 = cvtpk(acc[1][nt][2], acc[1][nt][3]);
            hrm[16*HRSTR + col] = (unsigned short)v01;
            hrm[17*HRSTR + col] = (unsigned short)(v01 >> 16);
            hrm[18*HRSTR + col] = (unsigned short)v23;
            hrm[19*HRSTR + col] = (unsigned short)(v23 >> 16);
            *(u32x2*)&hT[col*HTF + 16] = (u32x2){v01, v23};
        }
    }
    WB();

    // ---- GEMM2': t = h @ W2  (K=128, 64 MFMA; garbage rows clamped) ----
    #pragma unroll
    for (int nt = 0; nt < 8; ++nt) { acc[0][nt] = (f32x4){0,0,0,0}; acc[1][nt] = acc[0][nt]; }
    #pragma unroll
    for (int ks = 0; ks < 4; ++ks) {
        const short8 a0 = *(const short8*)&hrm[rlo*HRSTR + ks*32 + q*8];
        const short8 a1 = *(const short8*)&hrm[rhi*HRSTR + ks*32 + q*8];
        #pragma unroll
        for (int nt = 0; nt < 8; ++nt) {
            const short8 bfr = *(const short8*)&wsw2[(ks*8 + nt)*512 + l*8];
            acc[0][nt] = mfma16(a0, bfr, acc[0][nt]);
            acc[1][nt] = mfma16(a1, bfr, acc[1][nt]);
        }
    }
    WB();   // all hrm reads complete; tT may overwrite

    // ---- store t transposed: tT[col][row] ----
    #pragma unroll
    for (int nt = 0; nt < 8; ++nt) {
        const int col = ln15 + 16*nt;
        u32x2 w0 = { cvtpk(acc[0][nt][0], acc[0][nt][1]), cvtpk(acc[0][nt][2], acc[0][nt][3]) };
        *(u32x2*)&tT[col*HTSTR + q*4] = w0;                        // rows q*4..q*4+3
        if (q == 0) {
            u32x2 w1v = { cvtpk(acc[1][nt][0], acc[1][nt][1]), cvtpk(acc[1][nt][2], acc[1][nt][3]) };
            *(u32x2*)&tT[col*HTSTR + 16] = w1v;                    // rows 16..19
        }
    }
    // zero row-slots 20..23 for every col (lane covers col l and col l+64).
    // REQUIRED even though adjacency A-bits >=20 are zero: stale bytes can
    // encode bf16 Inf/NaN and IEEE 0*Inf = NaN would poison the MFMA dot.
    *(u32x2*)&tT[l*HTSTR + 20]        = (u32x2){0,0};
    *(u32x2*)&tT[(l + 64)*HTSTR + 20] = (u32x2){0,0};
    WB();

    // ---- y2 = adj @ t + b2  (16 MFMA; reuse acc) ----
    #pragma unroll
    for (int nt = 0; nt < 8; ++nt) {
        const float bv = b2[ln15 + 16*nt];
        f32x4 c0 = (f32x4){bv, bv, bv, bv};
        const short8 bfr = *(const short8*)&tT[(ln15 + 16*nt)*HTSTR + q*8];  // k=q*8+j
        acc[0][nt] = mfma16(adjf0, bfr, c0);
        acc[1][nt] = mfma16(adjf1, bfr, c0);
    }

    // ---- LN2 ----
    {
        float gv[8], bv[8];
        #pragma unroll
        for (int nt = 0; nt < 8; ++nt) { gv[nt] = g2[ln15+16*nt]; bv[nt] = be2[ln15+16*nt]; }
        #pragma unroll
        for (int mt = 0; mt < 2; ++mt) {
            #pragma unroll
            for (int reg = 0; reg < 4; ++reg) {
                float s = 0.f, sq = 0.f;
                #pragma unroll
                for (int nt = 0; nt < 8; ++nt) { float v = acc[mt][nt][reg]; s += v; sq += v*v; }
                #pragma unroll
                for (int m = 1; m < 16; m <<= 1) { s += __shfl_xor(s, m); sq += __shfl_xor(sq, m); }
                const float mean = s * (1.f/HID);
                const float var  = sq * (1.f/HID) - mean*mean;
                const float rstd = rsqrtf(fmaxf(var, 0.f) + EPS);
                #pragma unroll
                for (int nt = 0; nt < 8; ++nt)
                    acc[mt][nt][reg] = (acc[mt][nt][reg] - mean)*rstd*gv[nt] + bv[nt];
            }
        }
    }

    // ---- final: r = h + LN2(y2); gelu unimodal => max over rows = max(gelu(rmin), gelu(rmax)) ----
    #pragma unroll
    for (int nt = 0; nt < 8; ++nt) {
        const int col = ln15 + 16*nt;
        const ushort4 hv = *(const ushort4*)&hT[col*HTF + q*4];    // rows q*4..+3
        float rmax = -INFINITY, rmin = INFINITY, r;
        r = bf2f(hv.x) + acc[0][nt][0]; rmax = fmaxf(rmax, r); rmin = fminf(rmin, r);
        r = bf2f(hv.y) + acc[0][nt][1]; rmax = fmaxf(rmax, r); rmin = fminf(rmin, r);
        r = bf2f(hv.z) + acc[0][nt][2]; rmax = fmaxf(rmax, r); rmin = fminf(rmin, r);
        r = bf2f(hv.w) + acc[0][nt][3]; rmax = fmaxf(rmax, r); rmin = fminf(rmin, r);
        if (q == 0) {
            const ushort4 hw = *(const ushort4*)&hT[col*HTF + 16]; // rows 16..19
            r = bf2f(hw.x) + acc[1][nt][0]; rmax = fmaxf(rmax, r); rmin = fminf(rmin, r);
            r = bf2f(hw.y) + acc[1][nt][1]; rmax = fmaxf(rmax, r); rmin = fminf(rmin, r);
            r = bf2f(hw.z) + acc[1][nt][2]; rmax = fmaxf(rmax, r); rmin = fminf(rmin, r);
            r = bf2f(hw.w) + acc[1][nt][3]; rmax = fmaxf(rmax, r); rmin = fminf(rmin, r);
        }
        rmax = fmaxf(rmax, __shfl_xor(rmax, 16)); rmin = fminf(rmin, __shfl_xor(rmin, 16));
        rmax = fmaxf(rmax, __shfl_xor(rmax, 32)); rmin = fminf(rmin, __shfl_xor(rmin, 32));
        const float m0 = fmaxf(gelu_fast(rmax), gelu_fast(rmin));
        if (l < 16) out[(size_t)item*HID + 16*nt + l] = m0;
    }
}

extern "C" void kernel_launch(void* const* d_in, const int* in_sizes, int n_in,
                              void* d_out, int out_size, void* d_ws, size_t ws_size,
                              hipStream_t stream) {
    (void)n_in; (void)out_size; (void)ws_size;
    const float* x       = (const float*)d_in[0];
    const float* w_embed = (const float*)d_in[1];
    const float* b_embed = (const float*)d_in[2];
    const float* w1      = (const float*)d_in[3];
    const float* b1      = (const float*)d_in[4];
    const float* w2      = (const float*)d_in[5];
    const float* b2      = (const float*)d_in[6];
    const float* g1      = (const float*)d_in[7];
    const float* be1     = (const float*)d_in[8];
    const float* g2      = (const float*)d_in[9];
    const float* be2     = (const float*)d_in[10];
    float* out = (float*)d_out;

    // ws layout: [c1f 512B][wswM1 8192B][wsw2 32768B]
    unsigned char* ws = (unsigned char*)d_ws;
    float* c1f            = (float*)(ws + 0);
    unsigned short* wswM1 = (unsigned short*)(ws + 512);
    unsigned short* wsw2  = (unsigned short*)(ws + 512 + 8192);

    const int nItems  = in_sizes[0] / (N_NODES * IN_DIM);
    const int nBlocks = (nItems + IPB - 1) / IPB;

    prep_all<<<dim3(130), dim3(256), 0, stream>>>(w_embed, b_embed, w1, b1, w2,
                                                  wswM1, wsw2, c1f);
    hbond_main<<<dim3(nBlocks), dim3(128), 0, stream>>>(
        x, c1f, b2, g1, be1, g2, be2, wswM1, wsw2, out, nItems);
}

// Round 11
// 294.469 us; speedup vs baseline: 1.3671x; 1.0163x over previous
//
#include <hip/hip_runtime.h>
#include <math.h>

#define N_NODES 20
#define IN_DIM  9
#define HID     128
#define K_NBR   5
#define EPS     1e-5f
#define IPB     2          // items (waves) per 128-thread block

// ---- per-item LDS slice (bytes), regions with disjoint lifetimes alias at 0 ----
// phase A: xs (180 f32 = 720B @0) + adjx (20x16 bf16 = 640B @736)
// phase B: hrm (20 rows x 136 bf16 = 5440B @0)   h row-major, A-operand for t=h@W2
// phase C: tT  (128 cols x 24 bf16 = 6144B @0)   t transposed, B-operand for adj@t
// guard  : 16B zeros @6144 (col127/q3 B-frag overread target; never clobbered)
// hT     : h transposed [128 cols][20 rows] = 5120B @6160 (persists to final)
#define ADJX_OFF  736
#define HT_OFF    6160
#define SLICE     11280
#define HTSTR     24       // tT row-slots per col (multiple of 8 -> b128-aligned reads)
#define HRSTR     136      // hrm row stride (272B: 16B-mult, 4 mod 32 banks -> 2-way free)
#define HTF       20       // hT row-slots per col (40B stride, 8B-aligned b64 accesses)

typedef __attribute__((ext_vector_type(8))) short short8;   // 8 bf16 (4 VGPRs)
typedef __attribute__((ext_vector_type(4))) float f32x4;    // MFMA C/D frag
typedef __attribute__((ext_vector_type(2))) float f32x2;    // v_pk_*_f32 carrier
typedef __attribute__((ext_vector_type(2))) unsigned int u32x2;
typedef __attribute__((ext_vector_type(4))) unsigned int u32x4;

#define WB() __builtin_amdgcn_wave_barrier()

__device__ __forceinline__ unsigned short f2bf(float f) {
    unsigned u = __builtin_bit_cast(unsigned, f);
    u += 0x7fffu + ((u >> 16) & 1u);          // RNE
    return (unsigned short)(u >> 16);
}
#if __has_builtin(__builtin_amdgcn_cvt_pk_bf16_f32)
typedef __attribute__((ext_vector_type(2))) __bf16 bf16x2;
__device__ __forceinline__ unsigned cvtpk(float a, float b) {   // low=bf16(a), hi=bf16(b)
    bf16x2 r = __builtin_amdgcn_cvt_pk_bf16_f32(a, b);
    return __builtin_bit_cast(unsigned, r);
}
#else
__device__ __forceinline__ unsigned cvtpk(float a, float b) {
    return (unsigned)f2bf(a) | ((unsigned)f2bf(b) << 16);
}
#endif
__device__ __forceinline__ float bf2f(unsigned short h) {
    return __builtin_bit_cast(float, (unsigned)h << 16);
}
// unpack a bf16 pair (one u32) to two floats: lo = bits<<16, hi = bits&0xffff0000
__device__ __forceinline__ f32x2 unpk(unsigned u) {
    return (f32x2){ __builtin_bit_cast(float, u << 16),
                    __builtin_bit_cast(float, u & 0xffff0000u) };
}
// tanh-form GELU (|err| <~1e-3): x*u/(u+1), u=e^{2*0.79788456*(x+0.044715x^3)}
__device__ __forceinline__ float gelu_fast(float x) {
    float x2 = x * x;
    float y  = x * fmaf(x2, 0.07135806592f, 1.5957691216f);
    float u  = __expf(fminf(y, 60.0f));
    return x * u * __builtin_amdgcn_rcpf(u + 1.0f);
}
// packed 2-element gelu: polynomial in v_pk_*, exp/rcp scalar (no pk transcendentals)
__device__ __forceinline__ f32x2 gelu2(f32x2 x) {
    f32x2 x2 = x * x;
    f32x2 y  = x * (x2 * 0.07135806592f + 1.5957691216f);
    f32x2 u  = { __expf(fminf(y.x, 60.0f)), __expf(fminf(y.y, 60.0f)) };
    f32x2 n  = x * u;
    f32x2 d  = u + 1.0f;
    return (f32x2){ n.x * __builtin_amdgcn_rcpf(d.x), n.y * __builtin_amdgcn_rcpf(d.y) };
}
__device__ __forceinline__ f32x2 shfl2(f32x2 v, int m) {
    return (f32x2){ __shfl_xor(v.x, m), __shfl_xor(v.y, m) };
}

__device__ __forceinline__ f32x4 mfma16(short8 a, short8 b, f32x4 c) {
    return __builtin_amdgcn_mfma_f32_16x16x32_bf16(a, b, c, 0, 0, 0);
}

// ===== single prep kernel, fully parallel =====
__global__ void prep_all(const float* __restrict__ w_embed, const float* __restrict__ b_embed,
                         const float* __restrict__ w1, const float* __restrict__ b1,
                         const float* __restrict__ w2,
                         unsigned short* __restrict__ wswM1, unsigned short* __restrict__ wsw2,
                         float* __restrict__ c1f) {
    int tid = blockIdx.x * 256 + threadIdx.x;          // 33280 total -> 130 blocks
    if (tid < 16384) {
        int oid = tid >> 2, sub = tid & 3;
        int j = oid & 7, lane = (oid >> 3) & 63, nt = (oid >> 9) & 7;
        int k = (lane >> 4) * 8 + j;
        int n = nt * 16 + (lane & 15);
        float acc = 0.f;
        if (k < IN_DIM) {
            #pragma unroll 8
            for (int c = sub * 32; c < sub * 32 + 32; ++c)
                acc = fmaf(w_embed[k*HID + c], w1[c*HID + n], acc);
        }
        acc += __shfl_xor(acc, 1);
        acc += __shfl_xor(acc, 2);
        if (sub == 0) wswM1[oid] = (k < IN_DIM) ? f2bf(acc) : (unsigned short)0;
    } else if (tid < 16896) {
        int t2 = tid - 16384;
        int n = t2 >> 2, sub = t2 & 3;
        float cb = 0.f;
        #pragma unroll 8
        for (int c = sub * 32; c < sub * 32 + 32; ++c)
            cb = fmaf(b_embed[c], w1[c*HID + n], cb);
        cb += __shfl_xor(cb, 1);
        cb += __shfl_xor(cb, 2);
        if (sub == 0) c1f[n] = 5.0f * cb + b1[n];
    } else if (tid < 33280) {
        int i2 = tid - 16896;
        int j = i2 & 7, lane = (i2 >> 3) & 63, nt = (i2 >> 9) & 7, ks = (i2 >> 12) & 3;
        int k = ks * 32 + (lane >> 4) * 8 + j;
        int n = nt * 16 + (lane & 15);
        wsw2[i2] = f2bf(w2[k*HID + n]);
    }
}

// ===== main =====
__global__ __launch_bounds__(128, 3) void hbond_main(
    const float* __restrict__ x_in,
    const float* __restrict__ c1f, const float* __restrict__ b2,
    const float* __restrict__ g1, const float* __restrict__ be1,
    const float* __restrict__ g2, const float* __restrict__ be2,
    const unsigned short* __restrict__ wswM1, const unsigned short* __restrict__ wsw2,
    float* __restrict__ out, int nItems)
{
    __shared__ __align__(16) unsigned char smem[IPB * SLICE];

    const int l  = threadIdx.x & 63;
    const int wv = threadIdx.x >> 6;
    const int item = blockIdx.x * IPB + wv;
    if (item >= nItems) return;               // wave-uniform; no cross-wave barriers

    unsigned char* slice = smem + wv * SLICE;
    float*          xs   = (float*)(slice);                    // phase A
    unsigned short* adjx = (unsigned short*)(slice + ADJX_OFF);// phase A
    unsigned short* hrm  = (unsigned short*)(slice);           // phase B (aliases A)
    unsigned short* tT   = (unsigned short*)(slice);           // phase C (aliases B)
    unsigned short* hT   = (unsigned short*)(slice + HT_OFF);  // h residual, [col][20]

    const int ln15 = l & 15, q = l >> 4;
    const float* xb = x_in + (size_t)item * (N_NODES * IN_DIM);

    // guard for tT col127/q3 overread (bytes 6144..6160)
    if (l == 0) *(u32x4*)(slice + HTSTR * HID * 2) = (u32x4){0,0,0,0};

    // ---- stage x: 180 floats ----
    if (l < 45) ((float4*)xs)[l] = ((const float4*)xb)[l];
    WB();

    // ---- KNN: lane r = row r (r<20); bit-safe d2; tie -> lower index ----
    unsigned nbrp = 0;                        // 5 x 5-bit neighbor indices
    {
        const int rsel = (l < N_NODES) ? l : 0;
        const float px = xs[rsel*IN_DIM+6], py = xs[rsel*IN_DIM+7], pz = xs[rsel*IN_DIM+8];
        float d2[N_NODES];
        #pragma unroll
        for (int j = 0; j < N_NODES; ++j) {
            float dx = __fsub_rn(px, __shfl(px, j));
            float dy = __fsub_rn(py, __shfl(py, j));
            float dz = __fsub_rn(pz, __shfl(pz, j));
            d2[j] = __fadd_rn(__fadd_rn(__fmul_rn(dx,dx), __fmul_rn(dy,dy)), __fmul_rn(dz,dz));
        }
        unsigned used = 0u;
        #pragma unroll
        for (int k = 0; k < K_NBR; ++k) {
            float best = INFINITY; int bi = 0;
            #pragma unroll
            for (int j = 0; j < N_NODES; ++j) {
                bool take = (!((used >> j) & 1u)) && (d2[j] < best);
                best = take ? d2[j] : best;
                bi   = take ? j     : bi;
            }
            used |= (1u << bi);
            nbrp |= (unsigned)bi << (5*k);
        }
    }

    // ---- adjacency bitmask + bf16 A-fragments (k=q*8+j; bits >=20 always 0) ----
    unsigned amask = 0;
    #pragma unroll
    for (int j = 0; j < K_NBR; ++j) amask |= 1u << ((nbrp >> (5*j)) & 31);
    const unsigned am0 = (unsigned)__shfl((int)amask, ln15);
    const unsigned am1 = (unsigned)__shfl((int)amask, ln15 + 16);
    short8 adjf0, adjf1;
    #pragma unroll
    for (int j = 0; j < 8; ++j) {
        adjf0[j] = (short)(((am0 >> (q*8 + j)) & 1u) ? 0x3F80 : 0);
        adjf1[j] = (short)(((am1 >> (q*8 + j)) & 1u) ? 0x3F80 : 0);
    }

    // ---- agg1 on raw x (fp32 exact, packed sums) ----
    if (l < N_NODES) {
        f32x2 s01 = {0,0}, s23 = {0,0}, s45 = {0,0}, s67 = {0,0};
        float s8 = 0.f;
        #pragma unroll
        for (int j = 0; j < K_NBR; ++j) {
            const int b0 = ((nbrp >> (5*j)) & 31) * IN_DIM;
            s01 += (f32x2){xs[b0+0], xs[b0+1]};
            s23 += (f32x2){xs[b0+2], xs[b0+3]};
            s45 += (f32x2){xs[b0+4], xs[b0+5]};
            s67 += (f32x2){xs[b0+6], xs[b0+7]};
            s8  += xs[b0+8];
        }
        u32x4 p0 = { cvtpk(s01.x,s01.y), cvtpk(s23.x,s23.y), cvtpk(s45.x,s45.y), cvtpk(s67.x,s67.y) };
        u32x4 p1 = { cvtpk(s8,0.f), 0, 0, 0 };
        *(u32x4*)&adjx[l*16 + 0] = p0;
        *(u32x4*)&adjx[l*16 + 8] = p1;
    }
    WB();

    f32x4 acc[2][8];
    const int rlo = ln15, rhi = (ln15 + 16 > 19) ? 19 : ln15 + 16;  // clamp garbage rows

    // ---- GEMM1: y1 = adjx @ M1 + c1  (K=32, 16 MFMA; B zero for k>=9) ----
    {
        const short8 a0 = *(const short8*)&adjx[rlo*16 + (q & 1)*8];
        const short8 a1 = *(const short8*)&adjx[rhi*16 + (q & 1)*8];
        #pragma unroll
        for (int nt = 0; nt < 8; ++nt) {
            const float bv = c1f[ln15 + 16*nt];
            f32x4 c0 = (f32x4){bv, bv, bv, bv};
            const short8 bfr = *(const short8*)&wswM1[nt*512 + l*8];
            acc[0][nt] = mfma16(a0, bfr, c0);
            acc[1][nt] = mfma16(a1, bfr, c0);
        }
    }

    // ---- LN1 + GELU (packed f32x2) -> h as packed bf16-pair u32s ----
    unsigned hU01[2][8], hU23[2][8];   // [mt][nt]: rows (reg0,reg1) / (reg2,reg3)
    {
        float gva[8], bva[8];
        #pragma unroll
        for (int nt = 0; nt < 8; ++nt) { gva[nt] = g1[ln15+16*nt]; bva[nt] = be1[ln15+16*nt]; }
        #pragma unroll
        for (int mt = 0; mt < 2; ++mt) {
            f32x2 s01={0,0}, s23={0,0}, t01={0,0}, t23={0,0};
            #pragma unroll
            for (int nt = 0; nt < 8; ++nt) {
                f32x2 v01 = {acc[mt][nt][0], acc[mt][nt][1]};
                f32x2 v23 = {acc[mt][nt][2], acc[mt][nt][3]};
                s01 += v01; s23 += v23;
                t01 += v01*v01; t23 += v23*v23;
            }
            #pragma unroll
            for (int m = 1; m < 16; m <<= 1) {
                s01 += shfl2(s01,m); s23 += shfl2(s23,m);
                t01 += shfl2(t01,m); t23 += shfl2(t23,m);
            }
            f32x2 mean01 = s01 * (1.f/HID), mean23 = s23 * (1.f/HID);
            f32x2 var01  = t01 * (1.f/HID) - mean01*mean01;
            f32x2 var23  = t23 * (1.f/HID) - mean23*mean23;
            f32x2 rstd01 = { rsqrtf(fmaxf(var01.x,0.f)+EPS), rsqrtf(fmaxf(var01.y,0.f)+EPS) };
            f32x2 rstd23 = { rsqrtf(fmaxf(var23.x,0.f)+EPS), rsqrtf(fmaxf(var23.y,0.f)+EPS) };
            #pragma unroll
            for (int nt = 0; nt < 8; ++nt) {
                f32x2 v01 = {acc[mt][nt][0], acc[mt][nt][1]};
                f32x2 v23 = {acc[mt][nt][2], acc[mt][nt][3]};
                f32x2 h01 = gelu2((v01 - mean01) * rstd01 * gva[nt] + bva[nt]);
                f32x2 h23 = gelu2((v23 - mean23) * rstd23 * gva[nt] + bva[nt]);
                hU01[mt][nt] = cvtpk(h01.x, h01.y);
                hU23[mt][nt] = cvtpk(h23.x, h23.y);
            }
        }
    }
    WB();   // adjx/xs dead; GEMM1 A-reads complete

    // ---- scatter h: hrm row-major (GEMM2' A) + hT transposed (residual) ----
    #pragma unroll
    for (int nt = 0; nt < 8; ++nt) {
        const int col = ln15 + 16*nt;
        const unsigned u01 = hU01[0][nt], u23 = hU23[0][nt];
        hrm[(q*4+0)*HRSTR + col] = (unsigned short)u01;
        hrm[(q*4+1)*HRSTR + col] = (unsigned short)(u01 >> 16);
        hrm[(q*4+2)*HRSTR + col] = (unsigned short)u23;
        hrm[(q*4+3)*HRSTR + col] = (unsigned short)(u23 >> 16);
        *(u32x2*)&hT[col*HTF + q*4] = (u32x2){u01, u23};
        if (q == 0) {
            const unsigned v01 = hU01[1][nt], v23 = hU23[1][nt];
            hrm[16*HRSTR + col] = (unsigned short)v01;
            hrm[17*HRSTR + col] = (unsigned short)(v01 >> 16);
            hrm[18*HRSTR + col] = (unsigned short)v23;
            hrm[19*HRSTR + col] = (unsigned short)(v23 >> 16);
            *(u32x2*)&hT[col*HTF + 16] = (u32x2){v01, v23};
        }
    }
    WB();

    // ---- GEMM2': t = h @ W2  (K=128, 64 MFMA; garbage rows clamped) ----
    #pragma unroll
    for (int nt = 0; nt < 8; ++nt) { acc[0][nt] = (f32x4){0,0,0,0}; acc[1][nt] = acc[0][nt]; }
    #pragma unroll
    for (int ks = 0; ks < 4; ++ks) {
        const short8 a0 = *(const short8*)&hrm[rlo*HRSTR + ks*32 + q*8];
        const short8 a1 = *(const short8*)&hrm[rhi*HRSTR + ks*32 + q*8];
        #pragma unroll
        for (int nt = 0; nt < 8; ++nt) {
            const short8 bfr = *(const short8*)&wsw2[(ks*8 + nt)*512 + l*8];
            acc[0][nt] = mfma16(a0, bfr, acc[0][nt]);
            acc[1][nt] = mfma16(a1, bfr, acc[1][nt]);
        }
    }
    WB();   // all hrm reads complete; tT may overwrite

    // ---- store t transposed: tT[col][row] ----
    #pragma unroll
    for (int nt = 0; nt < 8; ++nt) {
        const int col = ln15 + 16*nt;
        u32x2 w0 = { cvtpk(acc[0][nt][0], acc[0][nt][1]), cvtpk(acc[0][nt][2], acc[0][nt][3]) };
        *(u32x2*)&tT[col*HTSTR + q*4] = w0;
        if (q == 0) {
            u32x2 w1v = { cvtpk(acc[1][nt][0], acc[1][nt][1]), cvtpk(acc[1][nt][2], acc[1][nt][3]) };
            *(u32x2*)&tT[col*HTSTR + 16] = w1v;
        }
    }
    // zero row-slots 20..23 (stale bytes can encode Inf/NaN; 0*Inf = NaN in MFMA)
    *(u32x2*)&tT[l*HTSTR + 20]        = (u32x2){0,0};
    *(u32x2*)&tT[(l + 64)*HTSTR + 20] = (u32x2){0,0};
    WB();

    // ---- y2 = adj @ t + b2  (16 MFMA; reuse acc) ----
    #pragma unroll
    for (int nt = 0; nt < 8; ++nt) {
        const float bv = b2[ln15 + 16*nt];
        f32x4 c0 = (f32x4){bv, bv, bv, bv};
        const short8 bfr = *(const short8*)&tT[(ln15 + 16*nt)*HTSTR + q*8];
        acc[0][nt] = mfma16(adjf0, bfr, c0);
        acc[1][nt] = mfma16(adjf1, bfr, c0);
    }

    // ---- LN2 stats (packed) ----
    f32x2 mean01[2], mean23[2], rstd01[2], rstd23[2];
    #pragma unroll
    for (int mt = 0; mt < 2; ++mt) {
        f32x2 s01={0,0}, s23={0,0}, t01={0,0}, t23={0,0};
        #pragma unroll
        for (int nt = 0; nt < 8; ++nt) {
            f32x2 v01 = {acc[mt][nt][0], acc[mt][nt][1]};
            f32x2 v23 = {acc[mt][nt][2], acc[mt][nt][3]};
            s01 += v01; s23 += v23;
            t01 += v01*v01; t23 += v23*v23;
        }
        #pragma unroll
        for (int m = 1; m < 16; m <<= 1) {
            s01 += shfl2(s01,m); s23 += shfl2(s23,m);
            t01 += shfl2(t01,m); t23 += shfl2(t23,m);
        }
        mean01[mt] = s01 * (1.f/HID); mean23[mt] = s23 * (1.f/HID);
        f32x2 v01 = t01 * (1.f/HID) - mean01[mt]*mean01[mt];
        f32x2 v23 = t23 * (1.f/HID) - mean23[mt]*mean23[mt];
        rstd01[mt] = (f32x2){ rsqrtf(fmaxf(v01.x,0.f)+EPS), rsqrtf(fmaxf(v01.y,0.f)+EPS) };
        rstd23[mt] = (f32x2){ rsqrtf(fmaxf(v23.x,0.f)+EPS), rsqrtf(fmaxf(v23.y,0.f)+EPS) };
    }

    // ---- fused LN2-apply + residual + minmax + gelu + store ----
    // gelu unimodal: max over rows = max(gelu(rmin), gelu(rmax))
    #pragma unroll
    for (int nt = 0; nt < 8; ++nt) {
        const int col = ln15 + 16*nt;
        const float gv = g2[col], bv = be2[col];
        f32x2 y01 = ((f32x2){acc[0][nt][0], acc[0][nt][1]} - mean01[0]) * rstd01[0] * gv + bv;
        f32x2 y23 = ((f32x2){acc[0][nt][2], acc[0][nt][3]} - mean23[0]) * rstd23[0] * gv + bv;
        const u32x2 hw = *(const u32x2*)&hT[col*HTF + q*4];
        f32x2 r01 = y01 + unpk(hw.x);
        f32x2 r23 = y23 + unpk(hw.y);
        float rmax = fmaxf(fmaxf(r01.x, r01.y), fmaxf(r23.x, r23.y));
        float rmin = fminf(fminf(r01.x, r01.y), fminf(r23.x, r23.y));
        if (q == 0) {
            f32x2 z01 = ((f32x2){acc[1][nt][0], acc[1][nt][1]} - mean01[1]) * rstd01[1] * gv + bv;
            f32x2 z23 = ((f32x2){acc[1][nt][2], acc[1][nt][3]} - mean23[1]) * rstd23[1] * gv + bv;
            const u32x2 hx = *(const u32x2*)&hT[col*HTF + 16];
            f32x2 w01 = z01 + unpk(hx.x);
            f32x2 w23 = z23 + unpk(hx.y);
            rmax = fmaxf(rmax, fmaxf(fmaxf(w01.x, w01.y), fmaxf(w23.x, w23.y)));
            rmin = fminf(rmin, fminf(fminf(w01.x, w01.y), fminf(w23.x, w23.y)));
        }
        rmax = fmaxf(rmax, __shfl_xor(rmax, 16)); rmin = fminf(rmin, __shfl_xor(rmin, 16));
        rmax = fmaxf(rmax, __shfl_xor(rmax, 32)); rmin = fminf(rmin, __shfl_xor(rmin, 32));
        const float m0 = fmaxf(gelu_fast(rmax), gelu_fast(rmin));
        if (l < 16) out[(size_t)item*HID + 16*nt + l] = m0;
    }
}

extern "C" void kernel_launch(void* const* d_in, const int* in_sizes, int n_in,
                              void* d_out, int out_size, void* d_ws, size_t ws_size,
                              hipStream_t stream) {
    (void)n_in; (void)out_size; (void)ws_size;
    const float* x       = (const float*)d_in[0];
    const float* w_embed = (const float*)d_in[1];
    const float* b_embed = (const float*)d_in[2];
    const float* w1      = (const float*)d_in[3];
    const float* b1      = (const float*)d_in[4];
    const float* w2      = (const float*)d_in[5];
    const float* b2      = (const float*)d_in[6];
    const float* g1      = (const float*)d_in[7];
    const float* be1     = (const float*)d_in[8];
    const float* g2      = (const float*)d_in[9];
    const float* be2     = (const float*)d_in[10];
    float* out = (float*)d_out;

    // ws layout: [c1f 512B][wswM1 8192B][wsw2 32768B]
    unsigned char* ws = (unsigned char*)d_ws;
    float* c1f            = (float*)(ws + 0);
    unsigned short* wswM1 = (unsigned short*)(ws + 512);
    unsigned short* wsw2  = (unsigned short*)(ws + 512 + 8192);

    const int nItems  = in_sizes[0] / (N_NODES * IN_DIM);
    const int nBlocks = (nItems + IPB - 1) / IPB;

    prep_all<<<dim3(130), dim3(256), 0, stream>>>(w_embed, b_embed, w1, b1, w2,
                                                  wswM1, wsw2, c1f);
    hbond_main<<<dim3(nBlocks), dim3(128), 0, stream>>>(
        x, c1f, b2, g1, be1, g2, be2, wswM1, wsw2, out, nItems);
}